// Round 1
// baseline (1118.434 us; speedup 1.0000x reference)
//
#include <hip/hip_runtime.h>
#include <cstdint>
#include <cstddef>

// Problem constants (from reference)
#define LSEQ 4096
#define DM 1024
#define DI 2048
#define DCONV 4
#define DRNK 64
#define DSTATE 16
#define DXW 96        // DRNK + 2*DSTATE
#define NCH 64        // number of scan chunks
#define CLEN 64       // LSEQ / NCH

__device__ __forceinline__ float siluf(float x) {
  return x / (1.f + __expf(-x));
}
__device__ __forceinline__ float softplusf(float x) {
  // stable log1p(exp(x))
  return fmaxf(x, 0.f) + log1pf(__expf(-fabsf(x)));
}

// ---------------------------------------------------------------------------
// Generic f32 NT GEMM: C[M,N] = A[M,K] * B[N,K]^T, optional softplus+bias epilogue
// 64x64 tile, BK=16, 256 threads, 4x4 per thread.
// ---------------------------------------------------------------------------
#define GBM 64
#define GBN 64
#define GBK 16

__global__ __launch_bounds__(256) void gemm_nt(
    const float* __restrict__ A, int lda,
    const float* __restrict__ B, int ldb,
    float* __restrict__ C, int ldc,
    int M, int N, int K,
    const float* __restrict__ bias, int epilogue)
{
  __shared__ float As[GBK][GBM + 4];
  __shared__ float Bs[GBK][GBN + 4];
  const int tid = threadIdx.x;
  const int m0 = blockIdx.y * GBM, n0 = blockIdx.x * GBN;
  const int lr = tid >> 2;          // 0..63 row of tile for loading
  const int lc = (tid & 3) << 2;    // 0,4,8,12 col group for loading
  const int tx = tid & 15, ty = tid >> 4;

  float acc[4][4] = {};

  for (int k0 = 0; k0 < K; k0 += GBK) {
    float4 va = make_float4(0.f, 0.f, 0.f, 0.f);
    float4 vb = make_float4(0.f, 0.f, 0.f, 0.f);
    const int am = m0 + lr;
    if (am < M) va = *(const float4*)(A + (size_t)am * lda + k0 + lc);
    const int bn = n0 + lr;
    if (bn < N) vb = *(const float4*)(B + (size_t)bn * ldb + k0 + lc);
    As[lc + 0][lr] = va.x; As[lc + 1][lr] = va.y;
    As[lc + 2][lr] = va.z; As[lc + 3][lr] = va.w;
    Bs[lc + 0][lr] = vb.x; Bs[lc + 1][lr] = vb.y;
    Bs[lc + 2][lr] = vb.z; Bs[lc + 3][lr] = vb.w;
    __syncthreads();
#pragma unroll
    for (int k = 0; k < GBK; ++k) {
      float a[4], b[4];
      *(float4*)a = *(const float4*)&As[k][ty << 2];
      *(float4*)b = *(const float4*)&Bs[k][tx << 2];
#pragma unroll
      for (int i = 0; i < 4; ++i)
#pragma unroll
        for (int j = 0; j < 4; ++j)
          acc[i][j] = fmaf(a[i], b[j], acc[i][j]);
    }
    __syncthreads();
  }

  // epilogue + store
#pragma unroll
  for (int i = 0; i < 4; ++i) {
    const int m = m0 + (ty << 2) + i;
    if (m >= M) continue;
    const int nbase = n0 + (tx << 2);
    float v[4];
#pragma unroll
    for (int j = 0; j < 4; ++j) {
      float t = acc[i][j];
      if (epilogue == 1) {
        int n = nbase + j;
        if (n < N) t = softplusf(t + bias[n]);
      }
      v[j] = t;
    }
    if (nbase + 3 < N) {
      *(float4*)(C + (size_t)m * ldc + nbase) = *(float4*)v;
    } else {
#pragma unroll
      for (int j = 0; j < 4; ++j)
        if (nbase + j < N) C[(size_t)m * ldc + nbase + j] = v[j];
    }
  }
}

// ---------------------------------------------------------------------------
// Depthwise causal conv (k=4) + bias + silu.  xi,xs: (LSEQ, DI) row-major.
// ---------------------------------------------------------------------------
__global__ __launch_bounds__(256) void conv_silu(
    const float* __restrict__ xi, const float* __restrict__ cw,
    const float* __restrict__ cb, float* __restrict__ xs)
{
  const int idx = blockIdx.x * 256 + threadIdx.x;   // over LSEQ*DI
  const int d = idx & (DI - 1);
  const int l = idx >> 11;
  float acc = cb[d];
#pragma unroll
  for (int j = 0; j < DCONV; ++j) {
    const int ls = l - (DCONV - 1) + j;
    if (ls >= 0) acc = fmaf(cw[d * DCONV + j], xi[(size_t)ls * DI + d], acc);
  }
  xs[idx] = siluf(acc);
}

// ---------------------------------------------------------------------------
// Scan pass 1: per-chunk local scan with h=0 init; emit P=prod(dA), S=end state.
// One thread per (chunk, d); 16 states per thread in registers.
// ---------------------------------------------------------------------------
__global__ __launch_bounds__(256) void scan_pass1(
    const float* __restrict__ delta, const float* __restrict__ xs,
    const float* __restrict__ dbl, const float* __restrict__ A_log,
    float* __restrict__ cP, float* __restrict__ cS)
{
  const int d = blockIdx.x * 256 + threadIdx.x;   // 0..DI-1
  const int c = blockIdx.y;                       // chunk
  __shared__ float Bsh[CLEN][DSTATE];
  for (int i = threadIdx.x; i < CLEN * DSTATE; i += 256) {
    const int l = i >> 4, n = i & 15;
    Bsh[l][n] = dbl[(size_t)(c * CLEN + l) * DXW + DRNK + n];
  }
  __syncthreads();

  float Av[DSTATE], h[DSTATE], P[DSTATE];
#pragma unroll
  for (int n = 0; n < DSTATE; ++n) {
    Av[n] = -__expf(A_log[d * DSTATE + n]);
    h[n] = 0.f;
    P[n] = 1.f;
  }
  for (int l = 0; l < CLEN; ++l) {
    const int gl = c * CLEN + l;
    const float dlt = delta[(size_t)gl * DI + d];
    const float du = dlt * xs[(size_t)gl * DI + d];
#pragma unroll
    for (int n = 0; n < DSTATE; ++n) {
      const float dA = __expf(dlt * Av[n]);
      h[n] = fmaf(dA, h[n], du * Bsh[l][n]);
      P[n] *= dA;
    }
  }
  const size_t base = (size_t)c * DI * DSTATE + (size_t)d * DSTATE;
#pragma unroll
  for (int n = 0; n < DSTATE; ++n) {
    cP[base + n] = P[n];
    cS[base + n] = h[n];
  }
}

// ---------------------------------------------------------------------------
// Scan pass 2: sequential carry over chunks; one thread per (d,n).
// ch0[c] = state entering chunk c.
// ---------------------------------------------------------------------------
__global__ __launch_bounds__(256) void scan_pass2(
    const float* __restrict__ cP, const float* __restrict__ cS,
    float* __restrict__ ch0)
{
  const int dn = blockIdx.x * 256 + threadIdx.x;  // 0..DI*DSTATE-1
  float h = 0.f;
  for (int c = 0; c < NCH; ++c) {
    const size_t o = (size_t)c * DI * DSTATE + dn;
    ch0[o] = h;
    h = fmaf(cP[o], h, cS[o]);
  }
}

// ---------------------------------------------------------------------------
// Scan pass 3: redo local scan seeded with ch0, emit y1 = sum_n h*C + xs*D.
// ---------------------------------------------------------------------------
__global__ __launch_bounds__(256) void scan_pass3(
    const float* __restrict__ delta, const float* __restrict__ xs,
    const float* __restrict__ dbl, const float* __restrict__ A_log,
    const float* __restrict__ ch0, const float* __restrict__ Dp,
    float* __restrict__ y1)
{
  const int d = blockIdx.x * 256 + threadIdx.x;
  const int c = blockIdx.y;
  __shared__ float Bsh[CLEN][DSTATE];
  __shared__ float Csh[CLEN][DSTATE];
  for (int i = threadIdx.x; i < CLEN * DSTATE; i += 256) {
    const int l = i >> 4, n = i & 15;
    const size_t row = (size_t)(c * CLEN + l) * DXW;
    Bsh[l][n] = dbl[row + DRNK + n];
    Csh[l][n] = dbl[row + DRNK + DSTATE + n];
  }
  __syncthreads();

  float Av[DSTATE], h[DSTATE];
  const size_t base = (size_t)c * DI * DSTATE + (size_t)d * DSTATE;
#pragma unroll
  for (int n = 0; n < DSTATE; ++n) {
    Av[n] = -__expf(A_log[d * DSTATE + n]);
    h[n] = ch0[base + n];
  }
  const float Dd = Dp[d];
  for (int l = 0; l < CLEN; ++l) {
    const int gl = c * CLEN + l;
    const float dlt = delta[(size_t)gl * DI + d];
    const float u = xs[(size_t)gl * DI + d];
    const float du = dlt * u;
    float y = 0.f;
#pragma unroll
    for (int n = 0; n < DSTATE; ++n) {
      const float dA = __expf(dlt * Av[n]);
      h[n] = fmaf(dA, h[n], du * Bsh[l][n]);
      y = fmaf(h[n], Csh[l][n], y);
    }
    y1[(size_t)gl * DI + d] = fmaf(u, Dd, y);
  }
}

// ---------------------------------------------------------------------------
// Gate: y1 *= silu(res), in place.
// ---------------------------------------------------------------------------
__global__ __launch_bounds__(256) void gate_silu(
    float* __restrict__ y1, const float* __restrict__ res)
{
  const int idx = blockIdx.x * 256 + threadIdx.x;
  y1[idx] = y1[idx] * siluf(res[idx]);
}

// ---------------------------------------------------------------------------
extern "C" void kernel_launch(void* const* d_in, const int* in_sizes, int n_in,
                              void* d_out, int out_size, void* d_ws, size_t ws_size,
                              hipStream_t stream) {
  (void)in_sizes; (void)n_in; (void)out_size; (void)ws_size;
  const float* x      = (const float*)d_in[0];   // (L, DM)
  const float* W_in   = (const float*)d_in[1];   // (2*DI, DM)
  const float* conv_w = (const float*)d_in[2];   // (DI,1,4)
  const float* conv_b = (const float*)d_in[3];   // (DI,)
  const float* W_x    = (const float*)d_in[4];   // (DXW, DI)
  const float* W_dt   = (const float*)d_in[5];   // (DI, DRNK)
  const float* b_dt   = (const float*)d_in[6];   // (DI,)
  const float* A_log  = (const float*)d_in[7];   // (DI, DSTATE)
  const float* Dp     = (const float*)d_in[8];   // (DI,)
  const float* W_out  = (const float*)d_in[9];   // (DM, DI)
  float* out = (float*)d_out;                    // (L, DM)

  // workspace layout (floats)
  const size_t LD = (size_t)LSEQ * DI;           // 8388608
  float* ws    = (float*)d_ws;
  float* xi    = ws;                 // LD (reused as y1 after conv)
  float* res   = xi    + LD;         // LD
  float* xs    = res   + LD;         // LD
  float* delta = xs    + LD;         // LD
  float* dbl   = delta + LD;         // LSEQ*DXW = 393216
  float* cP    = dbl   + (size_t)LSEQ * DXW;       // NCH*DI*DSTATE = 2097152
  float* cS    = cP    + (size_t)NCH * DI * DSTATE;
  float* ch0   = cS    + (size_t)NCH * DI * DSTATE;
  float* y1    = xi;   // alias: xi is dead after conv_silu

  // 1) xi = x @ W_in[0:DI].T ; res = x @ W_in[DI:2DI].T
  {
    dim3 grid(DI / GBN, LSEQ / GBM);
    hipLaunchKernelGGL(gemm_nt, grid, dim3(256), 0, stream,
                       x, DM, W_in, DM, xi, DI, LSEQ, DI, DM, nullptr, 0);
    hipLaunchKernelGGL(gemm_nt, grid, dim3(256), 0, stream,
                       x, DM, W_in + (size_t)DI * DM, DM, res, DI, LSEQ, DI, DM, nullptr, 0);
  }
  // 2) xs = silu(causal_depthwise_conv(xi) + conv_b)
  hipLaunchKernelGGL(conv_silu, dim3((LSEQ * DI) / 256), dim3(256), 0, stream,
                     xi, conv_w, conv_b, xs);
  // 3) dbl = xs @ W_x.T  (L, 96)
  {
    dim3 grid((DXW + GBN - 1) / GBN, LSEQ / GBM);
    hipLaunchKernelGGL(gemm_nt, grid, dim3(256), 0, stream,
                       xs, DI, W_x, DI, dbl, DXW, LSEQ, DXW, DI, nullptr, 0);
  }
  // 4) delta = softplus(dt_in @ W_dt.T + b_dt)   (dt_in = dbl[:, :DRNK])
  {
    dim3 grid(DI / GBN, LSEQ / GBM);
    hipLaunchKernelGGL(gemm_nt, grid, dim3(256), 0, stream,
                       dbl, DXW, W_dt, DRNK, delta, DI, LSEQ, DI, DRNK, b_dt, 1);
  }
  // 5) selective scan, chunked
  hipLaunchKernelGGL(scan_pass1, dim3(DI / 256, NCH), dim3(256), 0, stream,
                     delta, xs, dbl, A_log, cP, cS);
  hipLaunchKernelGGL(scan_pass2, dim3((DI * DSTATE) / 256), dim3(256), 0, stream,
                     cP, cS, ch0);
  hipLaunchKernelGGL(scan_pass3, dim3(DI / 256, NCH), dim3(256), 0, stream,
                     delta, xs, dbl, A_log, ch0, Dp, y1);
  // 6) y1 *= silu(res)
  hipLaunchKernelGGL(gate_silu, dim3((LSEQ * DI) / 256), dim3(256), 0, stream,
                     y1, res);
  // 7) out = y1 @ W_out.T
  {
    dim3 grid(DM / GBN, LSEQ / GBM);
    hipLaunchKernelGGL(gemm_nt, grid, dim3(256), 0, stream,
                       y1, DI, W_out, DI, out, DM, LSEQ, DM, DI, nullptr, 0);
  }
}

// Round 2
// 448.099 us; speedup vs baseline: 2.4960x; 2.4960x over previous
//
#include <hip/hip_runtime.h>
#include <cstdint>
#include <cstddef>

// Problem constants
#define LSEQ 4096
#define DM 1024
#define DI 2048
#define DCONV 4
#define DRNK 64
#define DSTATE 16
#define DXW 96        // DRNK + 2*DSTATE
#define NCH 64
#define CLEN 64       // LSEQ / NCH

typedef unsigned short ushort_t;
typedef __bf16 bfx8 __attribute__((ext_vector_type(8)));
typedef float  fx4  __attribute__((ext_vector_type(4)));

__device__ __forceinline__ float siluf(float x) { return x / (1.f + __expf(-x)); }
__device__ __forceinline__ float softplusf(float x) {
  return fmaxf(x, 0.f) + log1pf(__expf(-fabsf(x)));
}
__device__ __forceinline__ ushort_t f2b(float x) {
  __bf16 b = (__bf16)x;   // RNE
  return __builtin_bit_cast(ushort_t, b);
}
__device__ __forceinline__ void async16(const void* g, void* l) {
  __builtin_amdgcn_global_load_lds(
      (const __attribute__((address_space(1))) unsigned int*)g,
      (__attribute__((address_space(3))) unsigned int*)l, 16, 0, 0);
}

// ---------------------------------------------------------------------------
// bf16 MFMA NT GEMM: C[M,N] f32 = A[M,K]bf16 * B[N,K]bf16^T.
// 128x128 tile, BK=32, 256 threads (4 waves, 2x2), 16x16x32 MFMA, 4x4/wave.
// All of M,N multiples of 128; K multiple of 32. No bounds checks.
// ---------------------------------------------------------------------------
__global__ __launch_bounds__(256) void gemm_bf16(
    const ushort_t* __restrict__ A, int lda,
    const ushort_t* __restrict__ B, int ldb,
    float* __restrict__ C, int ldc, int K)
{
  __shared__ ushort_t As[128 * 32];
  __shared__ ushort_t Bs[128 * 32];
  const int tid  = threadIdx.x;
  const int m0   = blockIdx.y * 128, n0 = blockIdx.x * 128;
  const int lane = tid & 63;
  const int wave = tid >> 6;
  const int wm   = (wave >> 1) * 64, wn = (wave & 1) * 64;
  const int lm   = lane & 15;
  const int kg8  = (lane >> 4) * 8;
  // staging indices: thread t loads 16B chunk (t&3) of row (t>>2) in each half
  const int r0 = tid >> 2;
  const int c4 = (tid & 3) * 8;     // element offset within row (8 bf16 = 16B)

  fx4 acc[4][4] = {};

  const ushort_t* ga = A + (size_t)(m0 + r0) * lda + c4;
  const ushort_t* gb = B + (size_t)(n0 + r0) * ldb + c4;
  ushort_t* la0 = &As[r0 * 32 + c4];
  ushort_t* la1 = &As[(r0 + 64) * 32 + c4];
  ushort_t* lb0 = &Bs[r0 * 32 + c4];
  ushort_t* lb1 = &Bs[(r0 + 64) * 32 + c4];

  for (int k0 = 0; k0 < K; k0 += 32) {
    async16(ga + k0, la0);
    async16(ga + (size_t)64 * lda + k0, la1);
    async16(gb + k0, lb0);
    async16(gb + (size_t)64 * ldb + k0, lb1);
    __syncthreads();

    bfx8 af[4], bfr[4];
#pragma unroll
    for (int i = 0; i < 4; ++i)
      af[i] = *(const bfx8*)&As[(wm + i * 16 + lm) * 32 + kg8];
#pragma unroll
    for (int j = 0; j < 4; ++j)
      bfr[j] = *(const bfx8*)&Bs[(wn + j * 16 + lm) * 32 + kg8];
#pragma unroll
    for (int i = 0; i < 4; ++i)
#pragma unroll
      for (int j = 0; j < 4; ++j)
        acc[i][j] = __builtin_amdgcn_mfma_f32_16x16x32_bf16(af[i], bfr[j], acc[i][j], 0, 0, 0);
    __syncthreads();
  }

  // C/D layout (16x16): col = lane&15, row = (lane>>4)*4 + reg
  const int crow = (lane >> 4) * 4;
  const int ccol = lane & 15;
#pragma unroll
  for (int i = 0; i < 4; ++i)
#pragma unroll
    for (int r = 0; r < 4; ++r) {
      float* cp = C + (size_t)(m0 + wm + i * 16 + crow + r) * ldc + n0 + wn + ccol;
#pragma unroll
      for (int j = 0; j < 4; ++j)
        cp[j * 16] = acc[i][j][r];
    }
}

// ---------------------------------------------------------------------------
// Generic f32 NT GEMM (for accuracy-sensitive small GEMMs).
// epilogue: 0=store, 1=softplus(bias+x) store, 2=atomicAdd (split-K)
// KZ = K-chunk length (grid.z indexes chunks); pass KZ=K, grid.z=1 for full.
// ---------------------------------------------------------------------------
#define GBM 64
#define GBN 64
#define GBK 16

__global__ __launch_bounds__(256) void gemm_nt(
    const float* __restrict__ A, int lda,
    const float* __restrict__ B, int ldb,
    float* __restrict__ C, int ldc,
    int M, int N, int K, int KZ,
    const float* __restrict__ bias, int epilogue)
{
  __shared__ float As[GBK][GBM + 4];
  __shared__ float Bs[GBK][GBN + 4];
  const int tid = threadIdx.x;
  const int m0 = blockIdx.y * GBM, n0 = blockIdx.x * GBN;
  const int lr = tid >> 2;
  const int lc = (tid & 3) << 2;
  const int tx = tid & 15, ty = tid >> 4;
  const int kbeg = blockIdx.z * KZ;
  const int kend = min(K, kbeg + KZ);

  float acc[4][4] = {};

  for (int k0 = kbeg; k0 < kend; k0 += GBK) {
    float4 va = make_float4(0.f, 0.f, 0.f, 0.f);
    float4 vb = make_float4(0.f, 0.f, 0.f, 0.f);
    const int am = m0 + lr;
    if (am < M) va = *(const float4*)(A + (size_t)am * lda + k0 + lc);
    const int bn = n0 + lr;
    if (bn < N) vb = *(const float4*)(B + (size_t)bn * ldb + k0 + lc);
    As[lc + 0][lr] = va.x; As[lc + 1][lr] = va.y;
    As[lc + 2][lr] = va.z; As[lc + 3][lr] = va.w;
    Bs[lc + 0][lr] = vb.x; Bs[lc + 1][lr] = vb.y;
    Bs[lc + 2][lr] = vb.z; Bs[lc + 3][lr] = vb.w;
    __syncthreads();
#pragma unroll
    for (int k = 0; k < GBK; ++k) {
      float a[4], b[4];
      *(float4*)a = *(const float4*)&As[k][ty << 2];
      *(float4*)b = *(const float4*)&Bs[k][tx << 2];
#pragma unroll
      for (int i = 0; i < 4; ++i)
#pragma unroll
        for (int j = 0; j < 4; ++j)
          acc[i][j] = fmaf(a[i], b[j], acc[i][j]);
    }
    __syncthreads();
  }

#pragma unroll
  for (int i = 0; i < 4; ++i) {
    const int m = m0 + (ty << 2) + i;
    if (m >= M) continue;
    const int nbase = n0 + (tx << 2);
    if (epilogue == 2) {
#pragma unroll
      for (int j = 0; j < 4; ++j)
        if (nbase + j < N) atomicAdd(&C[(size_t)m * ldc + nbase + j], acc[i][j]);
      continue;
    }
    float v[4];
#pragma unroll
    for (int j = 0; j < 4; ++j) {
      float t = acc[i][j];
      if (epilogue == 1) {
        int n = nbase + j;
        if (n < N) t = softplusf(t + bias[n]);
      }
      v[j] = t;
    }
    if (nbase + 3 < N) {
      *(float4*)(C + (size_t)m * ldc + nbase) = *(float4*)v;
    } else {
#pragma unroll
      for (int j = 0; j < 4; ++j)
        if (nbase + j < N) C[(size_t)m * ldc + nbase + j] = v[j];
    }
  }
}

// ---------------------------------------------------------------------------
__global__ __launch_bounds__(256) void zero_f32(float* __restrict__ p, int n) {
  int i = blockIdx.x * 256 + threadIdx.x;
  if (i < n) p[i] = 0.f;
}

__global__ __launch_bounds__(256) void cast_f32_bf16(
    const float* __restrict__ in, ushort_t* __restrict__ out) {
  int i = (blockIdx.x * 256 + threadIdx.x) * 4;
  float4 v = *(const float4*)(in + i);
  ushort4 o;
  o.x = f2b(v.x); o.y = f2b(v.y); o.z = f2b(v.z); o.w = f2b(v.w);
  *(ushort4*)(out + i) = o;
}

// ---------------------------------------------------------------------------
// conv + silu: xi = xr[:, 0:DI] with row stride 2*DI
// ---------------------------------------------------------------------------
__global__ __launch_bounds__(256) void conv_silu(
    const float* __restrict__ xr, const float* __restrict__ cw,
    const float* __restrict__ cb, float* __restrict__ xs)
{
  const int idx = blockIdx.x * 256 + threadIdx.x;
  const int d = idx & (DI - 1);
  const int l = idx >> 11;
  float acc = cb[d];
#pragma unroll
  for (int j = 0; j < DCONV; ++j) {
    const int ls = l - (DCONV - 1) + j;
    if (ls >= 0) acc = fmaf(cw[d * DCONV + j], xr[(size_t)ls * (2 * DI) + d], acc);
  }
  xs[idx] = siluf(acc);
}

// ---------------------------------------------------------------------------
// Scan pass 1: per-chunk local scan, h=0 init; emit P=prod(dA), S=end state.
// ---------------------------------------------------------------------------
__global__ __launch_bounds__(256) void scan_pass1(
    const float* __restrict__ delta, const float* __restrict__ xs,
    const float* __restrict__ dbl, const float* __restrict__ A_log,
    float* __restrict__ cP, float* __restrict__ cS)
{
  const int d = blockIdx.x * 256 + threadIdx.x;
  const int c = blockIdx.y;
  __shared__ float Bsh[CLEN][DSTATE];
  for (int i = threadIdx.x; i < CLEN * DSTATE; i += 256) {
    const int l = i >> 4, n = i & 15;
    Bsh[l][n] = dbl[(size_t)(c * CLEN + l) * DXW + DRNK + n];
  }
  __syncthreads();

  float Av[DSTATE], h[DSTATE], P[DSTATE];
#pragma unroll
  for (int n = 0; n < DSTATE; ++n) {
    Av[n] = -__expf(A_log[d * DSTATE + n]);
    h[n] = 0.f; P[n] = 1.f;
  }
  for (int l = 0; l < CLEN; ++l) {
    const int gl = c * CLEN + l;
    const float dlt = delta[(size_t)gl * DI + d];
    const float du = dlt * xs[(size_t)gl * DI + d];
#pragma unroll
    for (int n = 0; n < DSTATE; ++n) {
      const float dA = __expf(dlt * Av[n]);
      h[n] = fmaf(dA, h[n], du * Bsh[l][n]);
      P[n] *= dA;
    }
  }
  const size_t base = (size_t)c * DI * DSTATE + (size_t)d * DSTATE;
#pragma unroll
  for (int n = 0; n < DSTATE; ++n) { cP[base + n] = P[n]; cS[base + n] = h[n]; }
}

// ---------------------------------------------------------------------------
// Scan pass 2: sequential carry over chunks; ch0 may alias cP.
// ---------------------------------------------------------------------------
__global__ __launch_bounds__(256) void scan_pass2(
    const float* __restrict__ cP, const float* __restrict__ cS,
    float* __restrict__ ch0)
{
  const int dn = blockIdx.x * 256 + threadIdx.x;
  float h = 0.f;
  for (int c = 0; c < NCH; ++c) {
    const size_t o = (size_t)c * DI * DSTATE + dn;
    const float p = cP[o], s = cS[o];
    ch0[o] = h;
    h = fmaf(p, h, s);
  }
}

// ---------------------------------------------------------------------------
// Scan pass 3: local scan seeded with ch0; y1 may alias delta (in-place).
// ---------------------------------------------------------------------------
__global__ __launch_bounds__(256) void scan_pass3(
    const float* __restrict__ delta, const float* __restrict__ xs,
    const float* __restrict__ dbl, const float* __restrict__ A_log,
    const float* __restrict__ ch0, const float* __restrict__ Dp,
    float* __restrict__ y1)
{
  const int d = blockIdx.x * 256 + threadIdx.x;
  const int c = blockIdx.y;
  __shared__ float Bsh[CLEN][DSTATE];
  __shared__ float Csh[CLEN][DSTATE];
  for (int i = threadIdx.x; i < CLEN * DSTATE; i += 256) {
    const int l = i >> 4, n = i & 15;
    const size_t row = (size_t)(c * CLEN + l) * DXW;
    Bsh[l][n] = dbl[row + DRNK + n];
    Csh[l][n] = dbl[row + DRNK + DSTATE + n];
  }
  __syncthreads();

  float Av[DSTATE], h[DSTATE];
  const size_t base = (size_t)c * DI * DSTATE + (size_t)d * DSTATE;
#pragma unroll
  for (int n = 0; n < DSTATE; ++n) {
    Av[n] = -__expf(A_log[d * DSTATE + n]);
    h[n] = ch0[base + n];
  }
  const float Dd = Dp[d];
  for (int l = 0; l < CLEN; ++l) {
    const int gl = c * CLEN + l;
    const float dlt = delta[(size_t)gl * DI + d];
    const float u = xs[(size_t)gl * DI + d];
    const float du = dlt * u;
    float y = 0.f;
#pragma unroll
    for (int n = 0; n < DSTATE; ++n) {
      const float dA = __expf(dlt * Av[n]);
      h[n] = fmaf(dA, h[n], du * Bsh[l][n]);
      y = fmaf(h[n], Csh[l][n], y);
    }
    y1[(size_t)gl * DI + d] = fmaf(u, Dd, y);
  }
}

// ---------------------------------------------------------------------------
// Gate + cast: y1b = bf16(y1 * silu(res)), res = xr[:, DI:2DI]
// ---------------------------------------------------------------------------
__global__ __launch_bounds__(256) void gate_cast(
    const float* __restrict__ y1, const float* __restrict__ xr,
    ushort_t* __restrict__ y1b)
{
  const int idx = (blockIdx.x * 256 + threadIdx.x) * 4;
  const int d = idx & (DI - 1);
  const int l = idx >> 11;
  float4 y = *(const float4*)(y1 + idx);
  float4 r = *(const float4*)(xr + (size_t)l * (2 * DI) + DI + d);
  ushort4 o;
  o.x = f2b(y.x * siluf(r.x));
  o.y = f2b(y.y * siluf(r.y));
  o.z = f2b(y.z * siluf(r.z));
  o.w = f2b(y.w * siluf(r.w));
  *(ushort4*)(y1b + idx) = o;
}

// ---------------------------------------------------------------------------
extern "C" void kernel_launch(void* const* d_in, const int* in_sizes, int n_in,
                              void* d_out, int out_size, void* d_ws, size_t ws_size,
                              hipStream_t stream) {
  (void)in_sizes; (void)n_in; (void)out_size; (void)ws_size;
  const float* x      = (const float*)d_in[0];
  const float* W_in   = (const float*)d_in[1];
  const float* conv_w = (const float*)d_in[2];
  const float* conv_b = (const float*)d_in[3];
  const float* W_x    = (const float*)d_in[4];
  const float* W_dt   = (const float*)d_in[5];
  const float* b_dt   = (const float*)d_in[6];
  const float* A_log  = (const float*)d_in[7];
  const float* Dp     = (const float*)d_in[8];
  const float* W_out  = (const float*)d_in[9];
  float* out = (float*)d_out;

  // workspace layout
  float* ws    = (float*)d_ws;
  float* xr    = ws;                          // (L, 2*DI) = 16M f
  float* xs    = xr    + (size_t)LSEQ * 2 * DI;   // 8M f
  float* delta = xs    + (size_t)LSEQ * DI;       // 8M f (later y1 in-place)
  float* dbl   = delta + (size_t)LSEQ * DI;       // L*96
  float* cP    = dbl   + (size_t)LSEQ * DXW;      // 2M f (later ch0 in-place)
  float* cS    = cP    + (size_t)NCH * DI * DSTATE;
  ushort_t* xb    = (ushort_t*)(cS + (size_t)NCH * DI * DSTATE);
  ushort_t* W_inb = xb    + (size_t)LSEQ * DM;        // 4M
  ushort_t* W_outb= W_inb + (size_t)2 * DI * DM;      // 2M
  ushort_t* y1b   = W_outb+ (size_t)DM * DI;          // 8M
  float* y1  = delta;   // in-place
  float* ch0 = cP;      // in-place

  // 0) casts to bf16
  hipLaunchKernelGGL(cast_f32_bf16, dim3((LSEQ * DM) / 1024), dim3(256), 0, stream, x, xb);
  hipLaunchKernelGGL(cast_f32_bf16, dim3((2 * DI * DM) / 1024), dim3(256), 0, stream, W_in, W_inb);
  hipLaunchKernelGGL(cast_f32_bf16, dim3((DM * DI) / 1024), dim3(256), 0, stream, W_out, W_outb);

  // 1) xr = x @ W_in.T  (M=4096, N=4096, K=1024) — xi | res fused
  hipLaunchKernelGGL(gemm_bf16, dim3((2 * DI) / 128, LSEQ / 128), dim3(256), 0, stream,
                     xb, DM, W_inb, DM, xr, 2 * DI, DM);

  // 2) xs = silu(conv(xi) + b)
  hipLaunchKernelGGL(conv_silu, dim3((LSEQ * DI) / 256), dim3(256), 0, stream,
                     xr, conv_w, conv_b, xs);

  // 3) dbl = xs @ W_x.T  (N=96, K=2048) — f32, split-K x4 with atomics
  hipLaunchKernelGGL(zero_f32, dim3((LSEQ * DXW + 255) / 256), dim3(256), 0, stream,
                     dbl, LSEQ * DXW);
  {
    dim3 grid((DXW + GBN - 1) / GBN, LSEQ / GBM, 4);
    hipLaunchKernelGGL(gemm_nt, grid, dim3(256), 0, stream,
                       xs, DI, W_x, DI, dbl, DXW, LSEQ, DXW, DI, DI / 4, nullptr, 2);
  }

  // 4) delta = softplus(dbl[:, :64] @ W_dt.T + b_dt)  (K=64) — f32
  {
    dim3 grid(DI / GBN, LSEQ / GBM, 1);
    hipLaunchKernelGGL(gemm_nt, grid, dim3(256), 0, stream,
                       dbl, DXW, W_dt, DRNK, delta, DI, LSEQ, DI, DRNK, DRNK, b_dt, 1);
  }

  // 5) chunked selective scan
  hipLaunchKernelGGL(scan_pass1, dim3(DI / 256, NCH), dim3(256), 0, stream,
                     delta, xs, dbl, A_log, cP, cS);
  hipLaunchKernelGGL(scan_pass2, dim3((DI * DSTATE) / 256), dim3(256), 0, stream,
                     cP, cS, ch0);
  hipLaunchKernelGGL(scan_pass3, dim3(DI / 256, NCH), dim3(256), 0, stream,
                     delta, xs, dbl, A_log, ch0, Dp, y1);

  // 6) y1b = bf16(y1 * silu(res))
  hipLaunchKernelGGL(gate_cast, dim3((LSEQ * DI) / 1024), dim3(256), 0, stream,
                     y1, xr, y1b);

  // 7) out = y1g @ W_out.T  (M=4096, N=1024, K=2048)
  hipLaunchKernelGGL(gemm_bf16, dim3(DM / 128, LSEQ / 128), dim3(256), 0, stream,
                     y1b, DI, W_outb, DI, out, DM, DI);
}

// Round 3
// 428.724 us; speedup vs baseline: 2.6087x; 1.0452x over previous
//
#include <hip/hip_runtime.h>
#include <cstdint>
#include <cstddef>

// Problem constants
#define LSEQ 4096
#define DM 1024
#define DI 2048
#define DCONV 4
#define DRNK 64
#define DSTATE 16
#define DXW 96        // DRNK + 2*DSTATE
#define NCH 64
#define CLEN 64       // LSEQ / NCH
#define KSPLIT 8      // split-K for dbl GEMM

typedef unsigned short ushort_t;
typedef __bf16 bfx8 __attribute__((ext_vector_type(8)));
typedef float  fx4  __attribute__((ext_vector_type(4)));

__device__ __forceinline__ float siluf(float x) { return x / (1.f + __expf(-x)); }
__device__ __forceinline__ float softplusf(float x) {
  return fmaxf(x, 0.f) + log1pf(__expf(-fabsf(x)));
}
__device__ __forceinline__ ushort_t f2b(float x) {
  __bf16 b = (__bf16)x;   // RNE
  return __builtin_bit_cast(ushort_t, b);
}
__device__ __forceinline__ float b2f(ushort_t u) {
  unsigned int x = ((unsigned int)u) << 16;
  return __builtin_bit_cast(float, x);
}
__device__ __forceinline__ void async16(const void* g, void* l) {
  __builtin_amdgcn_global_load_lds(
      (const __attribute__((address_space(1))) unsigned int*)g,
      (__attribute__((address_space(3))) unsigned int*)l, 16, 0, 0);
}

// ---------------------------------------------------------------------------
// bf16 MFMA NT GEMM: C[M,N] = A[M,K]bf16 * B[N,K]bf16^T.
// 128x128 tile, BK=32, 256 thr (4 waves 2x2), 16x16x32 MFMA, 4x4 frags/wave.
// OB=false: f32 C; OB=true: bf16 C. M,N %128==0, K %32==0.
// ---------------------------------------------------------------------------
template <bool OB>
__global__ __launch_bounds__(256) void gemm_bf16(
    const ushort_t* __restrict__ A, int lda,
    const ushort_t* __restrict__ B, int ldb,
    void* __restrict__ Cv, int ldc, int K)
{
  __shared__ ushort_t As[128 * 32];
  __shared__ ushort_t Bs[128 * 32];
  const int tid  = threadIdx.x;
  const int m0   = blockIdx.y * 128, n0 = blockIdx.x * 128;
  const int lane = tid & 63;
  const int wave = tid >> 6;
  const int wm   = (wave >> 1) * 64, wn = (wave & 1) * 64;
  const int lm   = lane & 15;
  const int kg8  = (lane >> 4) * 8;
  const int r0 = tid >> 2;
  const int c4 = (tid & 3) * 8;

  fx4 acc[4][4] = {};

  const ushort_t* ga = A + (size_t)(m0 + r0) * lda + c4;
  const ushort_t* gb = B + (size_t)(n0 + r0) * ldb + c4;
  ushort_t* la0 = &As[r0 * 32 + c4];
  ushort_t* la1 = &As[(r0 + 64) * 32 + c4];
  ushort_t* lb0 = &Bs[r0 * 32 + c4];
  ushort_t* lb1 = &Bs[(r0 + 64) * 32 + c4];

  for (int k0 = 0; k0 < K; k0 += 32) {
    async16(ga + k0, la0);
    async16(ga + (size_t)64 * lda + k0, la1);
    async16(gb + k0, lb0);
    async16(gb + (size_t)64 * ldb + k0, lb1);
    __syncthreads();

    bfx8 af[4], bfr[4];
#pragma unroll
    for (int i = 0; i < 4; ++i)
      af[i] = *(const bfx8*)&As[(wm + i * 16 + lm) * 32 + kg8];
#pragma unroll
    for (int j = 0; j < 4; ++j)
      bfr[j] = *(const bfx8*)&Bs[(wn + j * 16 + lm) * 32 + kg8];
#pragma unroll
    for (int i = 0; i < 4; ++i)
#pragma unroll
      for (int j = 0; j < 4; ++j)
        acc[i][j] = __builtin_amdgcn_mfma_f32_16x16x32_bf16(af[i], bfr[j], acc[i][j], 0, 0, 0);
    __syncthreads();
  }

  // C/D layout (16x16): col = lane&15, row = (lane>>4)*4 + reg
  const int crow = (lane >> 4) * 4;
  const int ccol = lane & 15;
#pragma unroll
  for (int i = 0; i < 4; ++i)
#pragma unroll
    for (int r = 0; r < 4; ++r) {
      const size_t rowoff = (size_t)(m0 + wm + i * 16 + crow + r) * ldc + n0 + wn + ccol;
      if (OB) {
        ushort_t* cp = (ushort_t*)Cv + rowoff;
#pragma unroll
        for (int j = 0; j < 4; ++j) cp[j * 16] = f2b(acc[i][j][r]);
      } else {
        float* cp = (float*)Cv + rowoff;
#pragma unroll
        for (int j = 0; j < 4; ++j) cp[j * 16] = acc[i][j][r];
      }
    }
}

// ---------------------------------------------------------------------------
// dbl GEMM: dbl[L,96] f32 += xsb[L,2048]bf16 @ W_xb[96,2048]bf16^T
// tile 128(M)x96(N), BK=32, split-K over grid.z, atomicAdd epilogue.
// ---------------------------------------------------------------------------
__global__ __launch_bounds__(256) void gemm_dbl(
    const ushort_t* __restrict__ A, const ushort_t* __restrict__ B,
    float* __restrict__ C)
{
  __shared__ ushort_t As[128 * 32];
  __shared__ ushort_t Bs[128 * 32];
  const int tid  = threadIdx.x;
  const int m0   = blockIdx.y * 128;
  const int lane = tid & 63;
  const int wave = tid >> 6;
  const int wm   = (wave >> 1) * 64, wn = (wave & 1) * 48;
  const int lm   = lane & 15;
  const int kg8  = (lane >> 4) * 8;
  const int r0 = tid >> 2;
  const int c4 = (tid & 3) * 8;
  const int kbeg = blockIdx.z * (DI / KSPLIT);

  fx4 acc[4][3] = {};

  const int brow1 = (r0 + 64 < DXW) ? r0 + 64 : DXW - 1;  // clamp; rows>=96 unused
  const ushort_t* ga  = A + (size_t)(m0 + r0) * DI + kbeg + c4;
  const ushort_t* gb0 = B + (size_t)r0 * DI + kbeg + c4;
  const ushort_t* gb1 = B + (size_t)brow1 * DI + kbeg + c4;
  ushort_t* la0 = &As[r0 * 32 + c4];
  ushort_t* la1 = &As[(r0 + 64) * 32 + c4];
  ushort_t* lb0 = &Bs[r0 * 32 + c4];
  ushort_t* lb1 = &Bs[(r0 + 64) * 32 + c4];

  for (int k0 = 0; k0 < DI / KSPLIT; k0 += 32) {
    async16(ga + k0, la0);
    async16(ga + (size_t)64 * DI + k0, la1);
    async16(gb0 + k0, lb0);
    async16(gb1 + k0, lb1);
    __syncthreads();

    bfx8 af[4], bfr[3];
#pragma unroll
    for (int i = 0; i < 4; ++i)
      af[i] = *(const bfx8*)&As[(wm + i * 16 + lm) * 32 + kg8];
#pragma unroll
    for (int j = 0; j < 3; ++j)
      bfr[j] = *(const bfx8*)&Bs[(wn + j * 16 + lm) * 32 + kg8];
#pragma unroll
    for (int i = 0; i < 4; ++i)
#pragma unroll
      for (int j = 0; j < 3; ++j)
        acc[i][j] = __builtin_amdgcn_mfma_f32_16x16x32_bf16(af[i], bfr[j], acc[i][j], 0, 0, 0);
    __syncthreads();
  }

  const int crow = (lane >> 4) * 4;
  const int ccol = lane & 15;
#pragma unroll
  for (int i = 0; i < 4; ++i)
#pragma unroll
    for (int r = 0; r < 4; ++r) {
      float* cp = C + (size_t)(m0 + wm + i * 16 + crow + r) * DXW + wn + ccol;
#pragma unroll
      for (int j = 0; j < 3; ++j)
        atomicAdd(cp + j * 16, acc[i][j][r]);
    }
}

// ---------------------------------------------------------------------------
// f32 NT GEMM (accuracy-critical delta GEMM). epilogue 1 = softplus(x+bias).
// ---------------------------------------------------------------------------
#define GBM 64
#define GBN 64
#define GBK 16

__global__ __launch_bounds__(256) void gemm_nt(
    const float* __restrict__ A, int lda,
    const float* __restrict__ B, int ldb,
    float* __restrict__ C, int ldc,
    int M, int N, int K,
    const float* __restrict__ bias, int epilogue)
{
  __shared__ float As[GBK][GBM + 4];
  __shared__ float Bs[GBK][GBN + 4];
  const int tid = threadIdx.x;
  const int m0 = blockIdx.y * GBM, n0 = blockIdx.x * GBN;
  const int lr = tid >> 2;
  const int lc = (tid & 3) << 2;
  const int tx = tid & 15, ty = tid >> 4;

  float acc[4][4] = {};

  for (int k0 = 0; k0 < K; k0 += GBK) {
    float4 va = make_float4(0.f, 0.f, 0.f, 0.f);
    float4 vb = make_float4(0.f, 0.f, 0.f, 0.f);
    const int am = m0 + lr;
    if (am < M) va = *(const float4*)(A + (size_t)am * lda + k0 + lc);
    const int bn = n0 + lr;
    if (bn < N) vb = *(const float4*)(B + (size_t)bn * ldb + k0 + lc);
    As[lc + 0][lr] = va.x; As[lc + 1][lr] = va.y;
    As[lc + 2][lr] = va.z; As[lc + 3][lr] = va.w;
    Bs[lc + 0][lr] = vb.x; Bs[lc + 1][lr] = vb.y;
    Bs[lc + 2][lr] = vb.z; Bs[lc + 3][lr] = vb.w;
    __syncthreads();
#pragma unroll
    for (int k = 0; k < GBK; ++k) {
      float a[4], b[4];
      *(float4*)a = *(const float4*)&As[k][ty << 2];
      *(float4*)b = *(const float4*)&Bs[k][tx << 2];
#pragma unroll
      for (int i = 0; i < 4; ++i)
#pragma unroll
        for (int j = 0; j < 4; ++j)
          acc[i][j] = fmaf(a[i], b[j], acc[i][j]);
    }
    __syncthreads();
  }

#pragma unroll
  for (int i = 0; i < 4; ++i) {
    const int m = m0 + (ty << 2) + i;
    if (m >= M) continue;
    const int nbase = n0 + (tx << 2);
    float v[4];
#pragma unroll
    for (int j = 0; j < 4; ++j) {
      float t = acc[i][j];
      if (epilogue == 1) {
        int n = nbase + j;
        if (n < N) t = softplusf(t + bias[n]);
      }
      v[j] = t;
    }
    if (nbase + 3 < N) {
      *(float4*)(C + (size_t)m * ldc + nbase) = *(float4*)v;
    } else {
#pragma unroll
      for (int j = 0; j < 4; ++j)
        if (nbase + j < N) C[(size_t)m * ldc + nbase + j] = v[j];
    }
  }
}

// ---------------------------------------------------------------------------
__global__ __launch_bounds__(256) void zero_f32(float* __restrict__ p, int n) {
  int i = blockIdx.x * 256 + threadIdx.x;
  if (i < n) p[i] = 0.f;
}

__global__ __launch_bounds__(256) void cast_f32_bf16(
    const float* __restrict__ in, ushort_t* __restrict__ out) {
  int i = (blockIdx.x * 256 + threadIdx.x) * 4;
  float4 v = *(const float4*)(in + i);
  ushort4 o;
  o.x = f2b(v.x); o.y = f2b(v.y); o.z = f2b(v.z); o.w = f2b(v.w);
  *(ushort4*)(out + i) = o;
}

// ---------------------------------------------------------------------------
// conv + silu from bf16 xr (row stride 2*DI); emits xs f32 + xsb bf16.
// width-2 per thread.
// ---------------------------------------------------------------------------
__global__ __launch_bounds__(256) void conv_silu_b(
    const ushort_t* __restrict__ xrb, const float* __restrict__ cw,
    const float* __restrict__ cb, float* __restrict__ xs,
    ushort_t* __restrict__ xsb)
{
  const int idx = (blockIdx.x * 256 + threadIdx.x) * 2;
  const int d = idx & (DI - 1);
  const int l = idx >> 11;
  float a0 = cb[d], a1 = cb[d + 1];
#pragma unroll
  for (int j = 0; j < DCONV; ++j) {
    const int ls = l - (DCONV - 1) + j;
    if (ls >= 0) {
      ushort2 u = *(const ushort2*)(xrb + (size_t)ls * (2 * DI) + d);
      a0 = fmaf(cw[d * DCONV + j], b2f(u.x), a0);
      a1 = fmaf(cw[(d + 1) * DCONV + j], b2f(u.y), a1);
    }
  }
  a0 = siluf(a0); a1 = siluf(a1);
  *(float2*)(xs + idx) = make_float2(a0, a1);
  ushort2 o; o.x = f2b(a0); o.y = f2b(a1);
  *(ushort2*)(xsb + idx) = o;
}

// ---------------------------------------------------------------------------
// Scan pass 1: per-chunk local scan, h=0 init; emit P=prod(dA), S=end state.
// ---------------------------------------------------------------------------
__global__ __launch_bounds__(256) void scan_pass1(
    const float* __restrict__ delta, const float* __restrict__ xs,
    const float* __restrict__ dbl, const float* __restrict__ A_log,
    float* __restrict__ cP, float* __restrict__ cS)
{
  const int d = blockIdx.x * 256 + threadIdx.x;
  const int c = blockIdx.y;
  __shared__ float Bsh[CLEN][DSTATE];
  for (int i = threadIdx.x; i < CLEN * DSTATE; i += 256) {
    const int l = i >> 4, n = i & 15;
    Bsh[l][n] = dbl[(size_t)(c * CLEN + l) * DXW + DRNK + n];
  }
  __syncthreads();

  float Av[DSTATE], h[DSTATE], P[DSTATE];
#pragma unroll
  for (int n = 0; n < DSTATE; ++n) {
    Av[n] = -__expf(A_log[d * DSTATE + n]);
    h[n] = 0.f; P[n] = 1.f;
  }
  for (int l = 0; l < CLEN; ++l) {
    const int gl = c * CLEN + l;
    const float dlt = delta[(size_t)gl * DI + d];
    const float du = dlt * xs[(size_t)gl * DI + d];
#pragma unroll
    for (int n = 0; n < DSTATE; ++n) {
      const float dA = __expf(dlt * Av[n]);
      h[n] = fmaf(dA, h[n], du * Bsh[l][n]);
      P[n] *= dA;
    }
  }
  const size_t base = (size_t)c * DI * DSTATE + (size_t)d * DSTATE;
#pragma unroll
  for (int n = 0; n < DSTATE; ++n) { cP[base + n] = P[n]; cS[base + n] = h[n]; }
}

// ---------------------------------------------------------------------------
// Scan pass 2: sequential carry over chunks; ch0 may alias cP.
// ---------------------------------------------------------------------------
__global__ __launch_bounds__(256) void scan_pass2(
    const float* __restrict__ cP, const float* __restrict__ cS,
    float* __restrict__ ch0)
{
  const int dn = blockIdx.x * 256 + threadIdx.x;
  float h = 0.f;
  for (int c = 0; c < NCH; ++c) {
    const size_t o = (size_t)c * DI * DSTATE + dn;
    const float p = cP[o], s = cS[o];
    ch0[o] = h;
    h = fmaf(p, h, s);
  }
}

// ---------------------------------------------------------------------------
// Scan pass 3 + gate fused: y1b = bf16( (scan_y + xs*D) * silu(res) ),
// res = xr[:, DI:2DI] in bf16.
// ---------------------------------------------------------------------------
__global__ __launch_bounds__(256) void scan_pass3(
    const float* __restrict__ delta, const float* __restrict__ xs,
    const float* __restrict__ dbl, const float* __restrict__ A_log,
    const float* __restrict__ ch0, const float* __restrict__ Dp,
    const ushort_t* __restrict__ xrb, ushort_t* __restrict__ y1b)
{
  const int d = blockIdx.x * 256 + threadIdx.x;
  const int c = blockIdx.y;
  __shared__ float Bsh[CLEN][DSTATE];
  __shared__ float Csh[CLEN][DSTATE];
  for (int i = threadIdx.x; i < CLEN * DSTATE; i += 256) {
    const int l = i >> 4, n = i & 15;
    const size_t row = (size_t)(c * CLEN + l) * DXW;
    Bsh[l][n] = dbl[row + DRNK + n];
    Csh[l][n] = dbl[row + DRNK + DSTATE + n];
  }
  __syncthreads();

  float Av[DSTATE], h[DSTATE];
  const size_t base = (size_t)c * DI * DSTATE + (size_t)d * DSTATE;
#pragma unroll
  for (int n = 0; n < DSTATE; ++n) {
    Av[n] = -__expf(A_log[d * DSTATE + n]);
    h[n] = ch0[base + n];
  }
  const float Dd = Dp[d];
  for (int l = 0; l < CLEN; ++l) {
    const int gl = c * CLEN + l;
    const float dlt = delta[(size_t)gl * DI + d];
    const float u = xs[(size_t)gl * DI + d];
    const float du = dlt * u;
    float y = 0.f;
#pragma unroll
    for (int n = 0; n < DSTATE; ++n) {
      const float dA = __expf(dlt * Av[n]);
      h[n] = fmaf(dA, h[n], du * Bsh[l][n]);
      y = fmaf(h[n], Csh[l][n], y);
    }
    y = fmaf(u, Dd, y);
    const float res = b2f(xrb[(size_t)gl * (2 * DI) + DI + d]);
    y1b[(size_t)gl * DI + d] = f2b(y * siluf(res));
  }
}

// ---------------------------------------------------------------------------
extern "C" void kernel_launch(void* const* d_in, const int* in_sizes, int n_in,
                              void* d_out, int out_size, void* d_ws, size_t ws_size,
                              hipStream_t stream) {
  (void)in_sizes; (void)n_in; (void)out_size; (void)ws_size;
  const float* x      = (const float*)d_in[0];
  const float* W_in   = (const float*)d_in[1];
  const float* conv_w = (const float*)d_in[2];
  const float* conv_b = (const float*)d_in[3];
  const float* W_x    = (const float*)d_in[4];
  const float* W_dt   = (const float*)d_in[5];
  const float* b_dt   = (const float*)d_in[6];
  const float* A_log  = (const float*)d_in[7];
  const float* Dp     = (const float*)d_in[8];
  const float* W_out  = (const float*)d_in[9];
  float* out = (float*)d_out;

  // workspace layout: f32 arrays first, then bf16 arrays
  float* ws    = (float*)d_ws;
  float* xs    = ws;                              // L*DI
  float* delta = xs    + (size_t)LSEQ * DI;       // L*DI
  float* dbl   = delta + (size_t)LSEQ * DI;       // L*96
  float* cP    = dbl   + (size_t)LSEQ * DXW;      // NCH*DI*DSTATE (later ch0)
  float* cS    = cP    + (size_t)NCH * DI * DSTATE;
  ushort_t* xrb   = (ushort_t*)(cS + (size_t)NCH * DI * DSTATE);  // L*2DI
  ushort_t* xsb   = xrb   + (size_t)LSEQ * 2 * DI;   // L*DI
  ushort_t* y1b   = xsb   + (size_t)LSEQ * DI;       // L*DI
  ushort_t* xb    = y1b   + (size_t)LSEQ * DI;       // L*DM
  ushort_t* W_inb = xb    + (size_t)LSEQ * DM;       // 2DI*DM
  ushort_t* W_outb= W_inb + (size_t)2 * DI * DM;     // DM*DI
  ushort_t* W_xb  = W_outb+ (size_t)DM * DI;         // 96*DI
  float* ch0 = cP;   // in-place

  // 0) casts to bf16
  hipLaunchKernelGGL(cast_f32_bf16, dim3((LSEQ * DM) / 1024), dim3(256), 0, stream, x, xb);
  hipLaunchKernelGGL(cast_f32_bf16, dim3((2 * DI * DM) / 1024), dim3(256), 0, stream, W_in, W_inb);
  hipLaunchKernelGGL(cast_f32_bf16, dim3((DM * DI) / 1024), dim3(256), 0, stream, W_out, W_outb);
  hipLaunchKernelGGL(cast_f32_bf16, dim3((DXW * DI) / 1024), dim3(256), 0, stream, W_x, W_xb);

  // 1) xrb = bf16(x @ W_in.T)  (M=4096, N=4096, K=1024)
  hipLaunchKernelGGL(HIP_KERNEL_NAME(gemm_bf16<true>),
                     dim3((2 * DI) / 128, LSEQ / 128), dim3(256), 0, stream,
                     xb, DM, W_inb, DM, (void*)xrb, 2 * DI, DM);

  // 2) xs, xsb = silu(conv(xi) + b)
  hipLaunchKernelGGL(conv_silu_b, dim3((LSEQ * DI) / 512), dim3(256), 0, stream,
                     xrb, conv_w, conv_b, xs, xsb);

  // 3) dbl = xsb @ W_xb.T  (N=96, K=2048) bf16 MFMA split-K=8 + atomics
  hipLaunchKernelGGL(zero_f32, dim3((LSEQ * DXW + 255) / 256), dim3(256), 0, stream,
                     dbl, LSEQ * DXW);
  hipLaunchKernelGGL(gemm_dbl, dim3(1, LSEQ / 128, KSPLIT), dim3(256), 0, stream,
                     xsb, W_xb, dbl);

  // 4) delta = softplus(dbl[:, :64] @ W_dt.T + b_dt)  (K=64) — f32 (accuracy)
  hipLaunchKernelGGL(gemm_nt, dim3(DI / GBN, LSEQ / GBM), dim3(256), 0, stream,
                     dbl, DXW, W_dt, DRNK, delta, DI, LSEQ, DI, DRNK, b_dt, 1);

  // 5) chunked selective scan
  hipLaunchKernelGGL(scan_pass1, dim3(DI / 256, NCH), dim3(256), 0, stream,
                     delta, xs, dbl, A_log, cP, cS);
  hipLaunchKernelGGL(scan_pass2, dim3((DI * DSTATE) / 256), dim3(256), 0, stream,
                     cP, cS, ch0);
  hipLaunchKernelGGL(scan_pass3, dim3(DI / 256, NCH), dim3(256), 0, stream,
                     delta, xs, dbl, A_log, ch0, Dp, xrb, y1b);

  // 6) out = y1b @ W_out.T  (M=4096, N=1024, K=2048) f32 out
  hipLaunchKernelGGL(HIP_KERNEL_NAME(gemm_bf16<false>),
                     dim3(DM / 128, LSEQ / 128), dim3(256), 0, stream,
                     y1b, DI, W_outb, DI, (void*)out, DM, DI);
}

// Round 4
// 361.755 us; speedup vs baseline: 3.0917x; 1.1851x over previous
//
#include <hip/hip_runtime.h>
#include <cstdint>
#include <cstddef>

// Problem constants
#define LSEQ 4096
#define DM 1024
#define DI 2048
#define DCONV 4
#define DRNK 64
#define DSTATE 16
#define DXW 96        // DRNK + 2*DSTATE
#define NCH 64
#define CLEN 64       // LSEQ / NCH
#define KSPLIT 8      // split-K for dbl GEMM

typedef unsigned short ushort_t;
typedef __bf16 bfx8 __attribute__((ext_vector_type(8)));
typedef float  fx4  __attribute__((ext_vector_type(4)));
typedef ushort_t usx8 __attribute__((ext_vector_type(8)));

__device__ __forceinline__ float siluf(float x) { return x / (1.f + __expf(-x)); }
__device__ __forceinline__ float softplusf(float x) {
  return fmaxf(x, 0.f) + log1pf(__expf(-fabsf(x)));
}
__device__ __forceinline__ ushort_t f2b(float x) {
  __bf16 b = (__bf16)x;   // RNE
  return __builtin_bit_cast(ushort_t, b);
}
__device__ __forceinline__ float b2f(ushort_t u) {
  unsigned int x = ((unsigned int)u) << 16;
  return __builtin_bit_cast(float, x);
}
__device__ __forceinline__ void async16(const void* g, void* l) {
  __builtin_amdgcn_global_load_lds(
      (const __attribute__((address_space(1))) unsigned int*)g,
      (__attribute__((address_space(3))) unsigned int*)l, 16, 0, 0);
}

// ---------------------------------------------------------------------------
// bf16 MFMA NT GEMM: C[M,N] = A[M,K]bf16 * B[N,K]bf16^T.
// 128x128 tile, BK=32, 256 thr (4 waves 2x2), 16x16x32 MFMA, 4x4 frags/wave.
// EPI: 0 = f32 store, 1 = bf16 store, 2 = f32 store of softplus(acc+bias[n]).
// M,N %128==0, K %32==0.
// ---------------------------------------------------------------------------
template <int EPI>
__global__ __launch_bounds__(256) void gemm_bf16(
    const ushort_t* __restrict__ A, int lda,
    const ushort_t* __restrict__ B, int ldb,
    void* __restrict__ Cv, int ldc, int K,
    const float* __restrict__ bias)
{
  __shared__ ushort_t As[128 * 32];
  __shared__ ushort_t Bs[128 * 32];
  const int tid  = threadIdx.x;
  const int m0   = blockIdx.y * 128, n0 = blockIdx.x * 128;
  const int lane = tid & 63;
  const int wave = tid >> 6;
  const int wm   = (wave >> 1) * 64, wn = (wave & 1) * 64;
  const int lm   = lane & 15;
  const int kg8  = (lane >> 4) * 8;
  const int r0 = tid >> 2;
  const int c4 = (tid & 3) * 8;

  fx4 acc[4][4] = {};

  const ushort_t* ga = A + (size_t)(m0 + r0) * lda + c4;
  const ushort_t* gb = B + (size_t)(n0 + r0) * ldb + c4;
  ushort_t* la0 = &As[r0 * 32 + c4];
  ushort_t* la1 = &As[(r0 + 64) * 32 + c4];
  ushort_t* lb0 = &Bs[r0 * 32 + c4];
  ushort_t* lb1 = &Bs[(r0 + 64) * 32 + c4];

  for (int k0 = 0; k0 < K; k0 += 32) {
    async16(ga + k0, la0);
    async16(ga + (size_t)64 * lda + k0, la1);
    async16(gb + k0, lb0);
    async16(gb + (size_t)64 * ldb + k0, lb1);
    __syncthreads();

    bfx8 af[4], bfr[4];
#pragma unroll
    for (int i = 0; i < 4; ++i)
      af[i] = *(const bfx8*)&As[(wm + i * 16 + lm) * 32 + kg8];
#pragma unroll
    for (int j = 0; j < 4; ++j)
      bfr[j] = *(const bfx8*)&Bs[(wn + j * 16 + lm) * 32 + kg8];
#pragma unroll
    for (int i = 0; i < 4; ++i)
#pragma unroll
      for (int j = 0; j < 4; ++j)
        acc[i][j] = __builtin_amdgcn_mfma_f32_16x16x32_bf16(af[i], bfr[j], acc[i][j], 0, 0, 0);
    __syncthreads();
  }

  // C/D layout (16x16): col = lane&15, row = (lane>>4)*4 + reg
  const int crow = (lane >> 4) * 4;
  const int ccol = lane & 15;
#pragma unroll
  for (int i = 0; i < 4; ++i)
#pragma unroll
    for (int r = 0; r < 4; ++r) {
      const size_t rowoff = (size_t)(m0 + wm + i * 16 + crow + r) * ldc + n0 + wn + ccol;
      if (EPI == 1) {
        ushort_t* cp = (ushort_t*)Cv + rowoff;
#pragma unroll
        for (int j = 0; j < 4; ++j) cp[j * 16] = f2b(acc[i][j][r]);
      } else if (EPI == 2) {
        float* cp = (float*)Cv + rowoff;
        const int nb = n0 + wn + ccol;
#pragma unroll
        for (int j = 0; j < 4; ++j)
          cp[j * 16] = softplusf(acc[i][j][r] + bias[nb + j * 16]);
      } else {
        float* cp = (float*)Cv + rowoff;
#pragma unroll
        for (int j = 0; j < 4; ++j) cp[j * 16] = acc[i][j][r];
      }
    }
}

// ---------------------------------------------------------------------------
// dbl GEMM: dbl[L,96] f32 += xsb[L,2048]bf16 @ W_xb[96,2048]bf16^T
// tile 128(M)x96(N), BK=32, split-K over grid.z, atomicAdd epilogue.
// ---------------------------------------------------------------------------
__global__ __launch_bounds__(256) void gemm_dbl(
    const ushort_t* __restrict__ A, const ushort_t* __restrict__ B,
    float* __restrict__ C)
{
  __shared__ ushort_t As[128 * 32];
  __shared__ ushort_t Bs[128 * 32];
  const int tid  = threadIdx.x;
  const int m0   = blockIdx.y * 128;
  const int lane = tid & 63;
  const int wave = tid >> 6;
  const int wm   = (wave >> 1) * 64, wn = (wave & 1) * 48;
  const int lm   = lane & 15;
  const int kg8  = (lane >> 4) * 8;
  const int r0 = tid >> 2;
  const int c4 = (tid & 3) * 8;
  const int kbeg = blockIdx.z * (DI / KSPLIT);

  fx4 acc[4][3] = {};

  const int brow1 = (r0 + 64 < DXW) ? r0 + 64 : DXW - 1;  // clamp; rows>=96 unused
  const ushort_t* ga  = A + (size_t)(m0 + r0) * DI + kbeg + c4;
  const ushort_t* gb0 = B + (size_t)r0 * DI + kbeg + c4;
  const ushort_t* gb1 = B + (size_t)brow1 * DI + kbeg + c4;
  ushort_t* la0 = &As[r0 * 32 + c4];
  ushort_t* la1 = &As[(r0 + 64) * 32 + c4];
  ushort_t* lb0 = &Bs[r0 * 32 + c4];
  ushort_t* lb1 = &Bs[(r0 + 64) * 32 + c4];

  for (int k0 = 0; k0 < DI / KSPLIT; k0 += 32) {
    async16(ga + k0, la0);
    async16(ga + (size_t)64 * DI + k0, la1);
    async16(gb0 + k0, lb0);
    async16(gb1 + k0, lb1);
    __syncthreads();

    bfx8 af[4], bfr[3];
#pragma unroll
    for (int i = 0; i < 4; ++i)
      af[i] = *(const bfx8*)&As[(wm + i * 16 + lm) * 32 + kg8];
#pragma unroll
    for (int j = 0; j < 3; ++j)
      bfr[j] = *(const bfx8*)&Bs[(wn + j * 16 + lm) * 32 + kg8];
#pragma unroll
    for (int i = 0; i < 4; ++i)
#pragma unroll
      for (int j = 0; j < 3; ++j)
        acc[i][j] = __builtin_amdgcn_mfma_f32_16x16x32_bf16(af[i], bfr[j], acc[i][j], 0, 0, 0);
    __syncthreads();
  }

  const int crow = (lane >> 4) * 4;
  const int ccol = lane & 15;
#pragma unroll
  for (int i = 0; i < 4; ++i)
#pragma unroll
    for (int r = 0; r < 4; ++r) {
      float* cp = C + (size_t)(m0 + wm + i * 16 + crow + r) * DXW + wn + ccol;
#pragma unroll
      for (int j = 0; j < 3; ++j)
        atomicAdd(cp + j * 16, acc[i][j][r]);
    }
}

// ---------------------------------------------------------------------------
__global__ __launch_bounds__(256) void zero_f32(float* __restrict__ p, int n) {
  int i = blockIdx.x * 256 + threadIdx.x;
  if (i < n) p[i] = 0.f;
}

// ---------------------------------------------------------------------------
// Fused cast of all 5 constant inputs to bf16 (one launch).
// Segment sizes are compile-time constants; each thread casts 4 floats.
// ---------------------------------------------------------------------------
#define CSZ0 (LSEQ * DM)        // x       4194304
#define CSZ1 (2 * DI * DM)      // W_in    4194304
#define CSZ2 (DM * DI)          // W_out   2097152
#define CSZ3 (DXW * DI)         // W_x      196608
#define CSZ4 (DI * DRNK)        // W_dt     131072
#define CTOT (CSZ0 + CSZ1 + CSZ2 + CSZ3 + CSZ4)

__global__ __launch_bounds__(256) void cast_all(
    const float* __restrict__ x, const float* __restrict__ W_in,
    const float* __restrict__ W_out, const float* __restrict__ W_x,
    const float* __restrict__ W_dt,
    ushort_t* __restrict__ xb, ushort_t* __restrict__ W_inb,
    ushort_t* __restrict__ W_outb, ushort_t* __restrict__ W_xb,
    ushort_t* __restrict__ W_dtb)
{
  int i = (blockIdx.x * 256 + threadIdx.x) * 4;
  if (i >= CTOT) return;
  const float* src; ushort_t* dst;
  if (i < CSZ0) { src = x + i; dst = xb + i; }
  else if (i < CSZ0 + CSZ1) { int o = i - CSZ0; src = W_in + o; dst = W_inb + o; }
  else if (i < CSZ0 + CSZ1 + CSZ2) { int o = i - CSZ0 - CSZ1; src = W_out + o; dst = W_outb + o; }
  else if (i < CSZ0 + CSZ1 + CSZ2 + CSZ3) { int o = i - CSZ0 - CSZ1 - CSZ2; src = W_x + o; dst = W_xb + o; }
  else { int o = i - CSZ0 - CSZ1 - CSZ2 - CSZ3; src = W_dt + o; dst = W_dtb + o; }
  float4 v = *(const float4*)src;
  ushort4 o4;
  o4.x = f2b(v.x); o4.y = f2b(v.y); o4.z = f2b(v.z); o4.w = f2b(v.w);
  *(ushort4*)dst = o4;
}

// ---------------------------------------------------------------------------
// cast dt_in = dbl[:, 0:64] f32 -> bf16 (row stride DXW -> DRNK)
// ---------------------------------------------------------------------------
__global__ __launch_bounds__(256) void cast_dtin(
    const float* __restrict__ dbl, ushort_t* __restrict__ dtb)
{
  const int i = blockIdx.x * 256 + threadIdx.x;   // over LSEQ*16
  const int row = i >> 4;
  const int c4 = (i & 15) * 4;
  float4 v = *(const float4*)(dbl + (size_t)row * DXW + c4);
  ushort4 o;
  o.x = f2b(v.x); o.y = f2b(v.y); o.z = f2b(v.z); o.w = f2b(v.w);
  *(ushort4*)(dtb + (size_t)row * DRNK + c4) = o;
}

// ---------------------------------------------------------------------------
// Sliding-window depthwise causal conv (k=4) + bias + silu, bf16 in/out.
// Thread owns 8 d-channels x 8 timesteps; 3-row history in registers.
// block = 256 threads = one l-chunk (8 rows) x all DI/8 d-groups.
// ---------------------------------------------------------------------------
__global__ __launch_bounds__(256) void conv2(
    const ushort_t* __restrict__ xrb, const float* __restrict__ cw,
    const float* __restrict__ cb, ushort_t* __restrict__ xsb)
{
  const int d0 = threadIdx.x * 8;        // 0..2040
  const int l0 = blockIdx.x * 8;         // 0..4088

  // per-channel weights (4 taps) + bias
  float4 w[8];
#pragma unroll
  for (int j = 0; j < 8; ++j) w[j] = *(const float4*)(cw + (size_t)(d0 + j) * DCONV);
  float cbv[8];
  *(float4*)&cbv[0] = *(const float4*)(cb + d0);
  *(float4*)&cbv[4] = *(const float4*)(cb + d0 + 4);

  float h0[8], h1[8], h2[8];
#pragma unroll
  for (int j = 0; j < 8; ++j) { h0[j] = 0.f; h1[j] = 0.f; h2[j] = 0.f; }
  if (l0 >= 3) {   // wave-uniform (all threads in block share l0)
    usx8 u0 = *(const usx8*)(xrb + (size_t)(l0 - 3) * (2 * DI) + d0);
    usx8 u1 = *(const usx8*)(xrb + (size_t)(l0 - 2) * (2 * DI) + d0);
    usx8 u2 = *(const usx8*)(xrb + (size_t)(l0 - 1) * (2 * DI) + d0);
#pragma unroll
    for (int j = 0; j < 8; ++j) { h0[j] = b2f(u0[j]); h1[j] = b2f(u1[j]); h2[j] = b2f(u2[j]); }
  }

#pragma unroll
  for (int i = 0; i < 8; ++i) {
    const int l = l0 + i;
    usx8 uc = *(const usx8*)(xrb + (size_t)l * (2 * DI) + d0);
    float c[8];
#pragma unroll
    for (int j = 0; j < 8; ++j) c[j] = b2f(uc[j]);
    usx8 o;
#pragma unroll
    for (int j = 0; j < 8; ++j) {
      float acc = cbv[j];
      acc = fmaf(w[j].x, h0[j], acc);
      acc = fmaf(w[j].y, h1[j], acc);
      acc = fmaf(w[j].z, h2[j], acc);
      acc = fmaf(w[j].w, c[j], acc);
      o[j] = f2b(siluf(acc));
    }
    *(usx8*)(xsb + (size_t)l * DI + d0) = o;
#pragma unroll
    for (int j = 0; j < 8; ++j) { h0[j] = h1[j]; h1[j] = h2[j]; h2[j] = c[j]; }
  }
}

// ---------------------------------------------------------------------------
// Scan pass 1: per-chunk local scan, h=0 init; emit P=prod(dA), S=end state.
// u (=xs) read as bf16.
// ---------------------------------------------------------------------------
__global__ __launch_bounds__(256) void scan_pass1(
    const float* __restrict__ delta, const ushort_t* __restrict__ xsb,
    const float* __restrict__ dbl, const float* __restrict__ A_log,
    float* __restrict__ cP, float* __restrict__ cS)
{
  const int d = blockIdx.x * 256 + threadIdx.x;
  const int c = blockIdx.y;
  __shared__ float Bsh[CLEN][DSTATE];
  for (int i = threadIdx.x; i < CLEN * DSTATE; i += 256) {
    const int l = i >> 4, n = i & 15;
    Bsh[l][n] = dbl[(size_t)(c * CLEN + l) * DXW + DRNK + n];
  }
  __syncthreads();

  float Av[DSTATE], h[DSTATE], P[DSTATE];
#pragma unroll
  for (int n = 0; n < DSTATE; ++n) {
    Av[n] = -__expf(A_log[d * DSTATE + n]);
    h[n] = 0.f; P[n] = 1.f;
  }
  for (int l = 0; l < CLEN; ++l) {
    const int gl = c * CLEN + l;
    const float dlt = delta[(size_t)gl * DI + d];
    const float du = dlt * b2f(xsb[(size_t)gl * DI + d]);
#pragma unroll
    for (int n = 0; n < DSTATE; ++n) {
      const float dA = __expf(dlt * Av[n]);
      h[n] = fmaf(dA, h[n], du * Bsh[l][n]);
      P[n] *= dA;
    }
  }
  const size_t base = (size_t)c * DI * DSTATE + (size_t)d * DSTATE;
#pragma unroll
  for (int n = 0; n < DSTATE; ++n) { cP[base + n] = P[n]; cS[base + n] = h[n]; }
}

// ---------------------------------------------------------------------------
// Scan pass 2: sequential carry over chunks; ch0 may alias cP.
// ---------------------------------------------------------------------------
__global__ __launch_bounds__(256) void scan_pass2(
    const float* __restrict__ cP, const float* __restrict__ cS,
    float* __restrict__ ch0)
{
  const int dn = blockIdx.x * 256 + threadIdx.x;
  float h = 0.f;
  for (int c = 0; c < NCH; ++c) {
    const size_t o = (size_t)c * DI * DSTATE + dn;
    const float p = cP[o], s = cS[o];
    ch0[o] = h;
    h = fmaf(p, h, s);
  }
}

// ---------------------------------------------------------------------------
// Scan pass 3 + gate fused: y1b = bf16( (scan_y + u*D) * silu(res) ).
// ---------------------------------------------------------------------------
__global__ __launch_bounds__(256) void scan_pass3(
    const float* __restrict__ delta, const ushort_t* __restrict__ xsb,
    const float* __restrict__ dbl, const float* __restrict__ A_log,
    const float* __restrict__ ch0, const float* __restrict__ Dp,
    const ushort_t* __restrict__ xrb, ushort_t* __restrict__ y1b)
{
  const int d = blockIdx.x * 256 + threadIdx.x;
  const int c = blockIdx.y;
  __shared__ float Bsh[CLEN][DSTATE];
  __shared__ float Csh[CLEN][DSTATE];
  for (int i = threadIdx.x; i < CLEN * DSTATE; i += 256) {
    const int l = i >> 4, n = i & 15;
    const size_t row = (size_t)(c * CLEN + l) * DXW;
    Bsh[l][n] = dbl[row + DRNK + n];
    Csh[l][n] = dbl[row + DRNK + DSTATE + n];
  }
  __syncthreads();

  float Av[DSTATE], h[DSTATE];
  const size_t base = (size_t)c * DI * DSTATE + (size_t)d * DSTATE;
#pragma unroll
  for (int n = 0; n < DSTATE; ++n) {
    Av[n] = -__expf(A_log[d * DSTATE + n]);
    h[n] = ch0[base + n];
  }
  const float Dd = Dp[d];
  for (int l = 0; l < CLEN; ++l) {
    const int gl = c * CLEN + l;
    const float dlt = delta[(size_t)gl * DI + d];
    const float u = b2f(xsb[(size_t)gl * DI + d]);
    const float du = dlt * u;
    float y = 0.f;
#pragma unroll
    for (int n = 0; n < DSTATE; ++n) {
      const float dA = __expf(dlt * Av[n]);
      h[n] = fmaf(dA, h[n], du * Bsh[l][n]);
      y = fmaf(h[n], Csh[l][n], y);
    }
    y = fmaf(u, Dd, y);
    const float res = b2f(xrb[(size_t)gl * (2 * DI) + DI + d]);
    y1b[(size_t)gl * DI + d] = f2b(y * siluf(res));
  }
}

// ---------------------------------------------------------------------------
extern "C" void kernel_launch(void* const* d_in, const int* in_sizes, int n_in,
                              void* d_out, int out_size, void* d_ws, size_t ws_size,
                              hipStream_t stream) {
  (void)in_sizes; (void)n_in; (void)out_size; (void)ws_size;
  const float* x      = (const float*)d_in[0];
  const float* W_in   = (const float*)d_in[1];
  const float* conv_w = (const float*)d_in[2];
  const float* conv_b = (const float*)d_in[3];
  const float* W_x    = (const float*)d_in[4];
  const float* W_dt   = (const float*)d_in[5];
  const float* b_dt   = (const float*)d_in[6];
  const float* A_log  = (const float*)d_in[7];
  const float* Dp     = (const float*)d_in[8];
  const float* W_out  = (const float*)d_in[9];
  float* out = (float*)d_out;

  // workspace layout: f32 arrays first, then bf16 arrays
  float* ws    = (float*)d_ws;
  float* delta = ws;                              // L*DI
  float* dbl   = delta + (size_t)LSEQ * DI;       // L*96
  float* cP    = dbl   + (size_t)LSEQ * DXW;      // NCH*DI*DSTATE (later ch0)
  float* cS    = cP    + (size_t)NCH * DI * DSTATE;
  ushort_t* xrb   = (ushort_t*)(cS + (size_t)NCH * DI * DSTATE);  // L*2DI
  ushort_t* xsb   = xrb   + (size_t)LSEQ * 2 * DI;   // L*DI
  ushort_t* y1b   = xsb   + (size_t)LSEQ * DI;       // L*DI
  ushort_t* xb    = y1b   + (size_t)LSEQ * DI;       // L*DM
  ushort_t* W_inb = xb    + (size_t)LSEQ * DM;       // 2DI*DM
  ushort_t* W_outb= W_inb + (size_t)2 * DI * DM;     // DM*DI
  ushort_t* W_xb  = W_outb+ (size_t)DM * DI;         // 96*DI
  ushort_t* W_dtb = W_xb  + (size_t)DXW * DI;        // DI*64
  ushort_t* dtb   = W_dtb + (size_t)DI * DRNK;       // L*64
  float* ch0 = cP;   // in-place

  // 0) all input casts in one launch
  hipLaunchKernelGGL(cast_all, dim3((CTOT / 4 + 255) / 256), dim3(256), 0, stream,
                     x, W_in, W_out, W_x, W_dt, xb, W_inb, W_outb, W_xb, W_dtb);

  // 1) xrb = bf16(x @ W_in.T)  (M=4096, N=4096, K=1024)
  hipLaunchKernelGGL(HIP_KERNEL_NAME(gemm_bf16<1>),
                     dim3((2 * DI) / 128, LSEQ / 128), dim3(256), 0, stream,
                     xb, DM, W_inb, DM, (void*)xrb, 2 * DI, DM, nullptr);

  // 2) xsb = bf16(silu(conv(xi) + b)) — sliding window
  hipLaunchKernelGGL(conv2, dim3(LSEQ / 8), dim3(256), 0, stream,
                     xrb, conv_w, conv_b, xsb);

  // 3) dbl = xsb @ W_xb.T  (N=96, K=2048) bf16 MFMA split-K=8 + atomics
  hipLaunchKernelGGL(zero_f32, dim3((LSEQ * DXW + 255) / 256), dim3(256), 0, stream,
                     dbl, LSEQ * DXW);
  hipLaunchKernelGGL(gemm_dbl, dim3(1, LSEQ / 128, KSPLIT), dim3(256), 0, stream,
                     xsb, W_xb, dbl);

  // 4) dtb = bf16(dbl[:, :64]); delta = softplus(dtb @ W_dtb.T + b_dt) f32
  hipLaunchKernelGGL(cast_dtin, dim3((LSEQ * 16) / 256), dim3(256), 0, stream,
                     dbl, dtb);
  hipLaunchKernelGGL(HIP_KERNEL_NAME(gemm_bf16<2>),
                     dim3(DI / 128, LSEQ / 128), dim3(256), 0, stream,
                     dtb, DRNK, W_dtb, DRNK, (void*)delta, DI, DRNK, b_dt);

  // 5) chunked selective scan
  hipLaunchKernelGGL(scan_pass1, dim3(DI / 256, NCH), dim3(256), 0, stream,
                     delta, xsb, dbl, A_log, cP, cS);
  hipLaunchKernelGGL(scan_pass2, dim3((DI * DSTATE) / 256), dim3(256), 0, stream,
                     cP, cS, ch0);
  hipLaunchKernelGGL(scan_pass3, dim3(DI / 256, NCH), dim3(256), 0, stream,
                     delta, xsb, dbl, A_log, ch0, Dp, xrb, y1b);

  // 6) out = y1b @ W_out.T  (M=4096, N=1024, K=2048) f32 out
  hipLaunchKernelGGL(HIP_KERNEL_NAME(gemm_bf16<0>),
                     dim3(DM / 128, LSEQ / 128), dim3(256), 0, stream,
                     y1b, DI, W_outb, DI, (void*)out, DM, DI, nullptr);
}

// Round 5
// 360.601 us; speedup vs baseline: 3.1016x; 1.0032x over previous
//
#include <hip/hip_runtime.h>
#include <cstdint>
#include <cstddef>

// Problem constants
#define LSEQ 4096
#define DM 1024
#define DI 2048
#define DCONV 4
#define DRNK 64
#define DSTATE 16
#define DXW 96        // DRNK + 2*DSTATE
#define NCH 64
#define CLEN 64       // LSEQ / NCH
#define KSPLIT 16     // split-K for dbl GEMM

typedef unsigned short ushort_t;
typedef __bf16 bfx8 __attribute__((ext_vector_type(8)));
typedef float  fx4  __attribute__((ext_vector_type(4)));
typedef ushort_t usx8 __attribute__((ext_vector_type(8)));

__device__ __forceinline__ float siluf(float x) { return x / (1.f + __expf(-x)); }
__device__ __forceinline__ float softplusf(float x) {
  return fmaxf(x, 0.f) + log1pf(__expf(-fabsf(x)));
}
__device__ __forceinline__ ushort_t f2b(float x) {
  __bf16 b = (__bf16)x;   // RNE
  return __builtin_bit_cast(ushort_t, b);
}
__device__ __forceinline__ float b2f(ushort_t u) {
  unsigned int x = ((unsigned int)u) << 16;
  return __builtin_bit_cast(float, x);
}
__device__ __forceinline__ void async16(const void* g, void* l) {
  __builtin_amdgcn_global_load_lds(
      (const __attribute__((address_space(1))) unsigned int*)g,
      (__attribute__((address_space(3))) unsigned int*)l, 16, 0, 0);
}

// ---------------------------------------------------------------------------
// bf16 MFMA NT GEMM: C[M,N] = A[M,K]bf16 * B[N,K]bf16^T.
// 128xBN tile (BN=128 or 64), BK=32, 256 thr (4 waves 2x2), 16x16x32 MFMA.
// XOR-swizzled LDS: chunk position p of row r holds global chunk p^((r>>1)&3)
// (applied via the global source address so global_load_lds dest stays
//  wave-uniform base + lane*16). Kills the 8-way read conflict of the
//  64B-row layout (2-way is free, m136).
// EPI: 0 = f32 store, 1 = bf16 store, 2 = bf16 store of softplus(acc+bias[n]).
// M %128==0, N %BN==0, K %32==0.
// ---------------------------------------------------------------------------
template <int EPI, int BN>
__global__ __launch_bounds__(256) void gemm_bf16(
    const ushort_t* __restrict__ A, int lda,
    const ushort_t* __restrict__ B, int ldb,
    void* __restrict__ Cv, int ldc, int K,
    const float* __restrict__ bias)
{
  constexpr int NJ = BN / 32;            // 4 (BN=128) or 2 (BN=64)
  __shared__ ushort_t As[128 * 32];
  __shared__ ushort_t Bs[BN * 32];
  const int tid  = threadIdx.x;
  const int m0   = blockIdx.y * 128, n0 = blockIdx.x * BN;
  const int lane = tid & 63;
  const int wave = tid >> 6;
  const int wm   = (wave >> 1) * 64, wn = (wave & 1) * (BN / 2);
  const int lm   = lane & 15;
  const int r0 = tid >> 2;
  // swizzled chunk for staging: this thread's LDS dest chunk is (tid&3),
  // so it must fetch global chunk (tid&3) ^ ((r0>>1)&3)
  const int cswz = (((tid & 3) ^ ((r0 >> 1) & 3))) * 8;
  // swizzled read offset: need chunk (lane>>4) of row R; key (R>>1)&3 reduces
  // to (lm>>1)&3 because wm + i*16 contributes multiples of 8 to R>>1.
  const int swz = (((lane >> 4) ^ ((lm >> 1) & 3))) * 8;

  fx4 acc[4][NJ] = {};

  const ushort_t* ga = A + (size_t)(m0 + r0) * lda + cswz;
  const ushort_t* gb = B + (size_t)(n0 + r0) * ldb + cswz;
  ushort_t* la0 = &As[r0 * 32 + (tid & 3) * 8];
  ushort_t* la1 = &As[(r0 + 64) * 32 + (tid & 3) * 8];
  ushort_t* lb0 = &Bs[r0 * 32 + (tid & 3) * 8];
  ushort_t* lb1 = (BN == 128) ? &Bs[(r0 + 64) * 32 + (tid & 3) * 8] : nullptr;

  for (int k0 = 0; k0 < K; k0 += 32) {
    async16(ga + k0, la0);
    async16(ga + (size_t)64 * lda + k0, la1);
    async16(gb + k0, lb0);
    if (BN == 128) async16(gb + (size_t)64 * ldb + k0, lb1);
    __syncthreads();

    bfx8 af[4], bfr[NJ];
#pragma unroll
    for (int i = 0; i < 4; ++i)
      af[i] = *(const bfx8*)&As[(wm + i * 16 + lm) * 32 + swz];
#pragma unroll
    for (int j = 0; j < NJ; ++j)
      bfr[j] = *(const bfx8*)&Bs[(wn + j * 16 + lm) * 32 + swz];
#pragma unroll
    for (int i = 0; i < 4; ++i)
#pragma unroll
      for (int j = 0; j < NJ; ++j)
        acc[i][j] = __builtin_amdgcn_mfma_f32_16x16x32_bf16(af[i], bfr[j], acc[i][j], 0, 0, 0);
    __syncthreads();
  }

  // C/D layout (16x16): col = lane&15, row = (lane>>4)*4 + reg
  const int crow = (lane >> 4) * 4;
  const int ccol = lane & 15;
#pragma unroll
  for (int i = 0; i < 4; ++i)
#pragma unroll
    for (int r = 0; r < 4; ++r) {
      const size_t rowoff = (size_t)(m0 + wm + i * 16 + crow + r) * ldc + n0 + wn + ccol;
      if (EPI == 1) {
        ushort_t* cp = (ushort_t*)Cv + rowoff;
#pragma unroll
        for (int j = 0; j < NJ; ++j) cp[j * 16] = f2b(acc[i][j][r]);
      } else if (EPI == 2) {
        ushort_t* cp = (ushort_t*)Cv + rowoff;
        const int nb = n0 + wn + ccol;
#pragma unroll
        for (int j = 0; j < NJ; ++j)
          cp[j * 16] = f2b(softplusf(acc[i][j][r] + bias[nb + j * 16]));
      } else {
        float* cp = (float*)Cv + rowoff;
#pragma unroll
        for (int j = 0; j < NJ; ++j) cp[j * 16] = acc[i][j][r];
      }
    }
}

// ---------------------------------------------------------------------------
// dbl GEMM: dbl[L,96] f32 += xsb[L,2048]bf16 @ W_xb[96,2048]bf16^T
// tile 128(M)x96(N), BK=32, split-K over grid.z, atomicAdd epilogue.
// Same XOR swizzle as gemm_bf16.
// ---------------------------------------------------------------------------
__global__ __launch_bounds__(256) void gemm_dbl(
    const ushort_t* __restrict__ A, const ushort_t* __restrict__ B,
    float* __restrict__ C)
{
  __shared__ ushort_t As[128 * 32];
  __shared__ ushort_t Bs[128 * 32];
  const int tid  = threadIdx.x;
  const int m0   = blockIdx.y * 128;
  const int lane = tid & 63;
  const int wave = tid >> 6;
  const int wm   = (wave >> 1) * 64, wn = (wave & 1) * 48;
  const int lm   = lane & 15;
  const int r0 = tid >> 2;
  const int cswz = (((tid & 3) ^ ((r0 >> 1) & 3))) * 8;
  const int swz  = (((lane >> 4) ^ ((lm >> 1) & 3))) * 8;
  const int kbeg = blockIdx.z * (DI / KSPLIT);

  fx4 acc[4][3] = {};

  const int brow1 = (r0 + 64 < DXW) ? r0 + 64 : DXW - 1;  // clamp; rows>=96 unused
  const ushort_t* ga  = A + (size_t)(m0 + r0) * DI + kbeg + cswz;
  const ushort_t* gb0 = B + (size_t)r0 * DI + kbeg + cswz;
  const ushort_t* gb1 = B + (size_t)brow1 * DI + kbeg + cswz;
  ushort_t* la0 = &As[r0 * 32 + (tid & 3) * 8];
  ushort_t* la1 = &As[(r0 + 64) * 32 + (tid & 3) * 8];
  ushort_t* lb0 = &Bs[r0 * 32 + (tid & 3) * 8];
  ushort_t* lb1 = &Bs[(r0 + 64) * 32 + (tid & 3) * 8];

  for (int k0 = 0; k0 < DI / KSPLIT; k0 += 32) {
    async16(ga + k0, la0);
    async16(ga + (size_t)64 * DI + k0, la1);
    async16(gb0 + k0, lb0);
    async16(gb1 + k0, lb1);
    __syncthreads();

    bfx8 af[4], bfr[3];
#pragma unroll
    for (int i = 0; i < 4; ++i)
      af[i] = *(const bfx8*)&As[(wm + i * 16 + lm) * 32 + swz];
#pragma unroll
    for (int j = 0; j < 3; ++j)
      bfr[j] = *(const bfx8*)&Bs[(wn + j * 16 + lm) * 32 + swz];
#pragma unroll
    for (int i = 0; i < 4; ++i)
#pragma unroll
      for (int j = 0; j < 3; ++j)
        acc[i][j] = __builtin_amdgcn_mfma_f32_16x16x32_bf16(af[i], bfr[j], acc[i][j], 0, 0, 0);
    __syncthreads();
  }

  const int crow = (lane >> 4) * 4;
  const int ccol = lane & 15;
#pragma unroll
  for (int i = 0; i < 4; ++i)
#pragma unroll
    for (int r = 0; r < 4; ++r) {
      float* cp = C + (size_t)(m0 + wm + i * 16 + crow + r) * DXW + wn + ccol;
#pragma unroll
      for (int j = 0; j < 3; ++j)
        atomicAdd(cp + j * 16, acc[i][j][r]);
    }
}

// ---------------------------------------------------------------------------
__global__ __launch_bounds__(256) void zero_f32(float* __restrict__ p, int n) {
  int i = blockIdx.x * 256 + threadIdx.x;
  if (i < n) p[i] = 0.f;
}

// ---------------------------------------------------------------------------
// Fused cast of all 5 constant inputs to bf16 (one launch).
// ---------------------------------------------------------------------------
#define CSZ0 (LSEQ * DM)        // x       4194304
#define CSZ1 (2 * DI * DM)      // W_in    4194304
#define CSZ2 (DM * DI)          // W_out   2097152
#define CSZ3 (DXW * DI)         // W_x      196608
#define CSZ4 (DI * DRNK)        // W_dt     131072
#define CTOT (CSZ0 + CSZ1 + CSZ2 + CSZ3 + CSZ4)

__global__ __launch_bounds__(256) void cast_all(
    const float* __restrict__ x, const float* __restrict__ W_in,
    const float* __restrict__ W_out, const float* __restrict__ W_x,
    const float* __restrict__ W_dt,
    ushort_t* __restrict__ xb, ushort_t* __restrict__ W_inb,
    ushort_t* __restrict__ W_outb, ushort_t* __restrict__ W_xb,
    ushort_t* __restrict__ W_dtb)
{
  int i = (blockIdx.x * 256 + threadIdx.x) * 4;
  if (i >= CTOT) return;
  const float* src; ushort_t* dst;
  if (i < CSZ0) { src = x + i; dst = xb + i; }
  else if (i < CSZ0 + CSZ1) { int o = i - CSZ0; src = W_in + o; dst = W_inb + o; }
  else if (i < CSZ0 + CSZ1 + CSZ2) { int o = i - CSZ0 - CSZ1; src = W_out + o; dst = W_outb + o; }
  else if (i < CSZ0 + CSZ1 + CSZ2 + CSZ3) { int o = i - CSZ0 - CSZ1 - CSZ2; src = W_x + o; dst = W_xb + o; }
  else { int o = i - CSZ0 - CSZ1 - CSZ2 - CSZ3; src = W_dt + o; dst = W_dtb + o; }
  float4 v = *(const float4*)src;
  ushort4 o4;
  o4.x = f2b(v.x); o4.y = f2b(v.y); o4.z = f2b(v.z); o4.w = f2b(v.w);
  *(ushort4*)dst = o4;
}

// ---------------------------------------------------------------------------
// cast dt_in = dbl[:, 0:64] f32 -> bf16 (row stride DXW -> DRNK)
// ---------------------------------------------------------------------------
__global__ __launch_bounds__(256) void cast_dtin(
    const float* __restrict__ dbl, ushort_t* __restrict__ dtb)
{
  const int i = blockIdx.x * 256 + threadIdx.x;   // over LSEQ*16
  const int row = i >> 4;
  const int c4 = (i & 15) * 4;
  float4 v = *(const float4*)(dbl + (size_t)row * DXW + c4);
  ushort4 o;
  o.x = f2b(v.x); o.y = f2b(v.y); o.z = f2b(v.z); o.w = f2b(v.w);
  *(ushort4*)(dtb + (size_t)row * DRNK + c4) = o;
}

// ---------------------------------------------------------------------------
// Sliding-window depthwise causal conv (k=4) + bias + silu, bf16 in/out.
// ---------------------------------------------------------------------------
__global__ __launch_bounds__(256) void conv2(
    const ushort_t* __restrict__ xrb, const float* __restrict__ cw,
    const float* __restrict__ cb, ushort_t* __restrict__ xsb)
{
  const int d0 = threadIdx.x * 8;
  const int l0 = blockIdx.x * 8;

  float4 w[8];
#pragma unroll
  for (int j = 0; j < 8; ++j) w[j] = *(const float4*)(cw + (size_t)(d0 + j) * DCONV);
  float cbv[8];
  *(float4*)&cbv[0] = *(const float4*)(cb + d0);
  *(float4*)&cbv[4] = *(const float4*)(cb + d0 + 4);

  float h0[8], h1[8], h2[8];
#pragma unroll
  for (int j = 0; j < 8; ++j) { h0[j] = 0.f; h1[j] = 0.f; h2[j] = 0.f; }
  if (l0 >= 3) {
    usx8 u0 = *(const usx8*)(xrb + (size_t)(l0 - 3) * (2 * DI) + d0);
    usx8 u1 = *(const usx8*)(xrb + (size_t)(l0 - 2) * (2 * DI) + d0);
    usx8 u2 = *(const usx8*)(xrb + (size_t)(l0 - 1) * (2 * DI) + d0);
#pragma unroll
    for (int j = 0; j < 8; ++j) { h0[j] = b2f(u0[j]); h1[j] = b2f(u1[j]); h2[j] = b2f(u2[j]); }
  }

#pragma unroll
  for (int i = 0; i < 8; ++i) {
    const int l = l0 + i;
    usx8 uc = *(const usx8*)(xrb + (size_t)l * (2 * DI) + d0);
    float c[8];
#pragma unroll
    for (int j = 0; j < 8; ++j) c[j] = b2f(uc[j]);
    usx8 o;
#pragma unroll
    for (int j = 0; j < 8; ++j) {
      float acc = cbv[j];
      acc = fmaf(w[j].x, h0[j], acc);
      acc = fmaf(w[j].y, h1[j], acc);
      acc = fmaf(w[j].z, h2[j], acc);
      acc = fmaf(w[j].w, c[j], acc);
      o[j] = f2b(siluf(acc));
    }
    *(usx8*)(xsb + (size_t)l * DI + d0) = o;
#pragma unroll
    for (int j = 0; j < 8; ++j) { h0[j] = h1[j]; h1[j] = h2[j]; h2[j] = c[j]; }
  }
}

// ---------------------------------------------------------------------------
// Scan pass 1: per-chunk local scan, h=0 init; emit P=prod(dA), S=end state.
// delta and u read as bf16.
// ---------------------------------------------------------------------------
__global__ __launch_bounds__(256) void scan_pass1(
    const ushort_t* __restrict__ deltab, const ushort_t* __restrict__ xsb,
    const float* __restrict__ dbl, const float* __restrict__ A_log,
    float* __restrict__ cP, float* __restrict__ cS)
{
  const int d = blockIdx.x * 256 + threadIdx.x;
  const int c = blockIdx.y;
  __shared__ float Bsh[CLEN][DSTATE];
  for (int i = threadIdx.x; i < CLEN * DSTATE; i += 256) {
    const int l = i >> 4, n = i & 15;
    Bsh[l][n] = dbl[(size_t)(c * CLEN + l) * DXW + DRNK + n];
  }
  __syncthreads();

  float Av[DSTATE], h[DSTATE], P[DSTATE];
#pragma unroll
  for (int n = 0; n < DSTATE; ++n) {
    Av[n] = -__expf(A_log[d * DSTATE + n]);
    h[n] = 0.f; P[n] = 1.f;
  }
  for (int l = 0; l < CLEN; ++l) {
    const int gl = c * CLEN + l;
    const float dlt = b2f(deltab[(size_t)gl * DI + d]);
    const float du = dlt * b2f(xsb[(size_t)gl * DI + d]);
#pragma unroll
    for (int n = 0; n < DSTATE; ++n) {
      const float dA = __expf(dlt * Av[n]);
      h[n] = fmaf(dA, h[n], du * Bsh[l][n]);
      P[n] *= dA;
    }
  }
  const size_t base = (size_t)c * DI * DSTATE + (size_t)d * DSTATE;
#pragma unroll
  for (int n = 0; n < DSTATE; ++n) { cP[base + n] = P[n]; cS[base + n] = h[n]; }
}

// ---------------------------------------------------------------------------
// Scan pass 2: sequential carry over chunks; ch0 may alias cP.
// ---------------------------------------------------------------------------
__global__ __launch_bounds__(256) void scan_pass2(
    const float* __restrict__ cP, const float* __restrict__ cS,
    float* __restrict__ ch0)
{
  const int dn = blockIdx.x * 256 + threadIdx.x;
  float h = 0.f;
  for (int c = 0; c < NCH; ++c) {
    const size_t o = (size_t)c * DI * DSTATE + dn;
    const float p = cP[o], s = cS[o];
    ch0[o] = h;
    h = fmaf(p, h, s);
  }
}

// ---------------------------------------------------------------------------
// Scan pass 3 + gate fused: y1b = bf16( (scan_y + u*D) * silu(res) ).
// ---------------------------------------------------------------------------
__global__ __launch_bounds__(256) void scan_pass3(
    const ushort_t* __restrict__ deltab, const ushort_t* __restrict__ xsb,
    const float* __restrict__ dbl, const float* __restrict__ A_log,
    const float* __restrict__ ch0, const float* __restrict__ Dp,
    const ushort_t* __restrict__ xrb, ushort_t* __restrict__ y1b)
{
  const int d = blockIdx.x * 256 + threadIdx.x;
  const int c = blockIdx.y;
  __shared__ float Bsh[CLEN][DSTATE];
  __shared__ float Csh[CLEN][DSTATE];
  for (int i = threadIdx.x; i < CLEN * DSTATE; i += 256) {
    const int l = i >> 4, n = i & 15;
    const size_t row = (size_t)(c * CLEN + l) * DXW;
    Bsh[l][n] = dbl[row + DRNK + n];
    Csh[l][n] = dbl[row + DRNK + DSTATE + n];
  }
  __syncthreads();

  float Av[DSTATE], h[DSTATE];
  const size_t base = (size_t)c * DI * DSTATE + (size_t)d * DSTATE;
#pragma unroll
  for (int n = 0; n < DSTATE; ++n) {
    Av[n] = -__expf(A_log[d * DSTATE + n]);
    h[n] = ch0[base + n];
  }
  const float Dd = Dp[d];
  for (int l = 0; l < CLEN; ++l) {
    const int gl = c * CLEN + l;
    const float dlt = b2f(deltab[(size_t)gl * DI + d]);
    const float u = b2f(xsb[(size_t)gl * DI + d]);
    const float du = dlt * u;
    float y = 0.f;
#pragma unroll
    for (int n = 0; n < DSTATE; ++n) {
      const float dA = __expf(dlt * Av[n]);
      h[n] = fmaf(dA, h[n], du * Bsh[l][n]);
      y = fmaf(h[n], Csh[l][n], y);
    }
    y = fmaf(u, Dd, y);
    const float res = b2f(xrb[(size_t)gl * (2 * DI) + DI + d]);
    y1b[(size_t)gl * DI + d] = f2b(y * siluf(res));
  }
}

// ---------------------------------------------------------------------------
extern "C" void kernel_launch(void* const* d_in, const int* in_sizes, int n_in,
                              void* d_out, int out_size, void* d_ws, size_t ws_size,
                              hipStream_t stream) {
  (void)in_sizes; (void)n_in; (void)out_size; (void)ws_size;
  const float* x      = (const float*)d_in[0];
  const float* W_in   = (const float*)d_in[1];
  const float* conv_w = (const float*)d_in[2];
  const float* conv_b = (const float*)d_in[3];
  const float* W_x    = (const float*)d_in[4];
  const float* W_dt   = (const float*)d_in[5];
  const float* b_dt   = (const float*)d_in[6];
  const float* A_log  = (const float*)d_in[7];
  const float* Dp     = (const float*)d_in[8];
  const float* W_out  = (const float*)d_in[9];
  float* out = (float*)d_out;

  // workspace layout: f32 arrays first, then bf16 arrays
  float* ws    = (float*)d_ws;
  float* dbl   = ws;                              // L*96
  float* cP    = dbl   + (size_t)LSEQ * DXW;      // NCH*DI*DSTATE (later ch0)
  float* cS    = cP    + (size_t)NCH * DI * DSTATE;
  ushort_t* deltab = (ushort_t*)(cS + (size_t)NCH * DI * DSTATE);  // L*DI
  ushort_t* xrb   = deltab + (size_t)LSEQ * DI;      // L*2DI
  ushort_t* xsb   = xrb   + (size_t)LSEQ * 2 * DI;   // L*DI
  ushort_t* y1b   = xsb   + (size_t)LSEQ * DI;       // L*DI
  ushort_t* xb    = y1b   + (size_t)LSEQ * DI;       // L*DM
  ushort_t* W_inb = xb    + (size_t)LSEQ * DM;       // 2DI*DM
  ushort_t* W_outb= W_inb + (size_t)2 * DI * DM;     // DM*DI
  ushort_t* W_xb  = W_outb+ (size_t)DM * DI;         // 96*DI
  ushort_t* W_dtb = W_xb  + (size_t)DXW * DI;        // DI*64
  ushort_t* dtb   = W_dtb + (size_t)DI * DRNK;       // L*64
  float* ch0 = cP;   // in-place

  // 0) all input casts in one launch
  hipLaunchKernelGGL(cast_all, dim3((CTOT / 4 + 255) / 256), dim3(256), 0, stream,
                     x, W_in, W_out, W_x, W_dt, xb, W_inb, W_outb, W_xb, W_dtb);

  // 1) xrb = bf16(x @ W_in.T)  (M=4096, N=4096, K=1024)
  hipLaunchKernelGGL(HIP_KERNEL_NAME(gemm_bf16<1, 128>),
                     dim3((2 * DI) / 128, LSEQ / 128), dim3(256), 0, stream,
                     xb, DM, W_inb, DM, (void*)xrb, 2 * DI, DM, nullptr);

  // 2) xsb = bf16(silu(conv(xi) + b)) — sliding window
  hipLaunchKernelGGL(conv2, dim3(LSEQ / 8), dim3(256), 0, stream,
                     xrb, conv_w, conv_b, xsb);

  // 3) dbl = xsb @ W_xb.T  (N=96, K=2048) bf16 MFMA split-K=16 + atomics
  hipLaunchKernelGGL(zero_f32, dim3((LSEQ * DXW + 255) / 256), dim3(256), 0, stream,
                     dbl, LSEQ * DXW);
  hipLaunchKernelGGL(gemm_dbl, dim3(1, LSEQ / 128, KSPLIT), dim3(256), 0, stream,
                     xsb, W_xb, dbl);

  // 4) dtb = bf16(dbl[:, :64]); deltab = bf16(softplus(dtb @ W_dtb.T + b_dt))
  hipLaunchKernelGGL(cast_dtin, dim3((LSEQ * 16) / 256), dim3(256), 0, stream,
                     dbl, dtb);
  hipLaunchKernelGGL(HIP_KERNEL_NAME(gemm_bf16<2, 128>),
                     dim3(DI / 128, LSEQ / 128), dim3(256), 0, stream,
                     dtb, DRNK, W_dtb, DRNK, (void*)deltab, DI, DRNK, b_dt);

  // 5) chunked selective scan
  hipLaunchKernelGGL(scan_pass1, dim3(DI / 256, NCH), dim3(256), 0, stream,
                     deltab, xsb, dbl, A_log, cP, cS);
  hipLaunchKernelGGL(scan_pass2, dim3((DI * DSTATE) / 256), dim3(256), 0, stream,
                     cP, cS, ch0);
  hipLaunchKernelGGL(scan_pass3, dim3(DI / 256, NCH), dim3(256), 0, stream,
                     deltab, xsb, dbl, A_log, ch0, Dp, xrb, y1b);

  // 6) out = y1b @ W_out.T  (M=4096, N=1024, K=2048), 128x64 tile -> 512 blocks
  hipLaunchKernelGGL(HIP_KERNEL_NAME(gemm_bf16<0, 64>),
                     dim3(DM / 64, LSEQ / 128), dim3(256), 0, stream,
                     y1b, DI, W_outb, DI, (void*)out, DM, DI, nullptr);
}